// Round 1
// baseline (2227.030 us; speedup 1.0000x reference)
//
#include <hip/hip_runtime.h>

#define N_NODES 50000
#define N_EDGES 800000
#define IN_DIM 128
#define HID 256
#define OUT_DIM 64
#define N_CONV 4

// ---------------- CSR build ----------------
__global__ void k_count(const int* __restrict__ dst, int* __restrict__ cnt, int ne){
  int e = blockIdx.x*blockDim.x + threadIdx.x;
  if (e < ne) atomicAdd(&cnt[dst[e]], 1);
}

__global__ void k_scan(const int* __restrict__ cnt, int* __restrict__ row_ptr, int n){
  __shared__ int sd[1024];
  __shared__ int carry;
  if (threadIdx.x == 0) carry = 0;
  __syncthreads();
  for (int base = 0; base < n; base += 1024){
    int i = base + (int)threadIdx.x;
    int v = (i < n) ? cnt[i] : 0;
    sd[threadIdx.x] = v;
    __syncthreads();
    #pragma unroll
    for (int off = 1; off < 1024; off <<= 1){
      int t = (threadIdx.x >= (unsigned)off) ? sd[threadIdx.x - off] : 0;
      __syncthreads();
      sd[threadIdx.x] += t;
      __syncthreads();
    }
    if (i < n) row_ptr[i+1] = carry + sd[threadIdx.x];
    __syncthreads();
    if (threadIdx.x == 1023) carry += sd[1023];
    __syncthreads();
  }
  if (threadIdx.x == 0) row_ptr[0] = 0;
}

__global__ void k_fill(const int* __restrict__ src, const int* __restrict__ dst,
                       int* __restrict__ cursor, int* __restrict__ esrc, int ne){
  int e = blockIdx.x*blockDim.x + threadIdx.x;
  if (e < ne){
    int p = atomicAdd(&cursor[dst[e]], 1);
    esrc[p] = src[e];
  }
}

// ---------------- aggregation: agg[n] = x[n] + sum_{e in in(n)} x[src_e] ----------------
template<int D>
__global__ void k_aggregate(const float* __restrict__ x, const int* __restrict__ row_ptr,
                            const int* __restrict__ esrc, float* __restrict__ agg, int n){
  int gw  = (int)((blockIdx.x*(size_t)blockDim.x + threadIdx.x) >> 6);
  int lane = threadIdx.x & 63;
  if (gw >= n) return;
  if (D == 256){
    float4 acc = *(const float4*)(x + (size_t)gw*D + lane*4);
    int e1 = row_ptr[gw+1];
    for (int e = row_ptr[gw]; e < e1; ++e){
      int s = esrc[e];
      float4 v = *(const float4*)(x + (size_t)s*D + lane*4);
      acc.x += v.x; acc.y += v.y; acc.z += v.z; acc.w += v.w;
    }
    *(float4*)(agg + (size_t)gw*D + lane*4) = acc;
  } else {
    float2 acc = *(const float2*)(x + (size_t)gw*D + lane*2);
    int e1 = row_ptr[gw+1];
    for (int e = row_ptr[gw]; e < e1; ++e){
      int s = esrc[e];
      float2 v = *(const float2*)(x + (size_t)s*D + lane*2);
      acc.x += v.x; acc.y += v.y;
    }
    *(float2*)(agg + (size_t)gw*D + lane*2) = acc;
  }
}

// ---------------- column stats (mean/var over node axis) ----------------
__global__ void k_colstats(const float* __restrict__ t, float* __restrict__ sums, int M){
  int c = threadIdx.x;          // 256 columns
  int r0 = blockIdx.x * 256;
  int r1 = min(r0 + 256, M);
  float s = 0.f, s2 = 0.f;
  for (int r = r0; r < r1; ++r){
    float v = t[(size_t)r*HID + c];
    s += v; s2 = fmaf(v, v, s2);
  }
  atomicAdd(&sums[c], s);
  atomicAdd(&sums[HID + c], s2);
}

__global__ void k_finstats(const float* __restrict__ sums, float* __restrict__ stats, int M){
  int c = threadIdx.x;
  float mean = sums[c] / (float)M;
  float var  = sums[HID + c] / (float)M - mean*mean;
  stats[c] = mean;
  stats[HID + c] = rsqrtf(var + 1e-5f);
}

__global__ void k_bnrelu(const float* __restrict__ t, const float* __restrict__ stats,
                         const float* __restrict__ gamma, const float* __restrict__ beta,
                         float* __restrict__ o, int M){
  int idx = blockIdx.x*blockDim.x + threadIdx.x;
  if (idx >= M*(HID/4)) return;
  int cg = (idx & 63) * 4;
  float4 v = *(const float4*)(t + (size_t)idx*4);
  float r[4] = {v.x, v.y, v.z, v.w};
  float4 o4;
  float* po = &o4.x;
  #pragma unroll
  for (int j = 0; j < 4; ++j){
    int c = cg + j;
    float y = (r[j] - stats[c]) * stats[HID + c] * gamma[c] + beta[c];
    po[j] = y > 0.f ? y : 0.f;
  }
  *(float4*)(o + (size_t)idx*4) = o4;
}

// ---------------- fp32 tiled GEMM: C[M,N] = A[M,K] @ B[K,N] ----------------
// MODE 0: store; MODE 1: store + bias[col]; MODE 2: accumulate into C
template<int MODE>
__global__ __launch_bounds__(256) void k_gemm(const float* __restrict__ A, const float* __restrict__ B,
                       float* __restrict__ C, const float* __restrict__ bias,
                       int M, int N, int K){
  __shared__ float Ast[16][68];   // transposed A tile: Ast[k][r]
  __shared__ float Bs[16][68];    // Bs[k][c]
  int n0 = blockIdx.x * 64, m0 = blockIdx.y * 64;
  int tid = threadIdx.x;
  int tx = tid & 15, ty = tid >> 4;
  float c[4][4] = {};
  for (int k0 = 0; k0 < K; k0 += 16){
    #pragma unroll
    for (int i = 0; i < 4; ++i){
      int e = tid + i*256;
      int r = e >> 4, kk = e & 15;
      int gr = m0 + r;
      Ast[kk][r] = (gr < M) ? A[(size_t)gr*K + k0 + kk] : 0.f;
    }
    #pragma unroll
    for (int i = 0; i < 4; ++i){
      int e = tid + i*256;
      int r = e >> 6, cc = e & 63;
      Bs[r][cc] = B[(size_t)(k0 + r)*N + n0 + cc];
    }
    __syncthreads();
    #pragma unroll
    for (int kk = 0; kk < 16; ++kk){
      float4 a4 = *(const float4*)(&Ast[kk][ty*4]);
      float4 b4 = *(const float4*)(&Bs[kk][tx*4]);
      float av[4] = {a4.x, a4.y, a4.z, a4.w};
      float bv[4] = {b4.x, b4.y, b4.z, b4.w};
      #pragma unroll
      for (int i = 0; i < 4; ++i)
        #pragma unroll
        for (int j = 0; j < 4; ++j)
          c[i][j] = fmaf(av[i], bv[j], c[i][j]);
    }
    __syncthreads();
  }
  #pragma unroll
  for (int i = 0; i < 4; ++i){
    int r = m0 + ty*4 + i;
    if (r >= M) continue;
    float* Cr = C + (size_t)r*N + n0 + tx*4;
    #pragma unroll
    for (int j = 0; j < 4; ++j){
      if (MODE == 0)      Cr[j] = c[i][j];
      else if (MODE == 1) Cr[j] = c[i][j] + bias[n0 + tx*4 + j];
      else                Cr[j] += c[i][j];
    }
  }
}

__global__ void k_biasall(const float* __restrict__ p0b, const float* __restrict__ pb,
                          float* __restrict__ ball){
  int c = threadIdx.x;  // 64
  float v = p0b[c];
  #pragma unroll
  for (int i = 0; i < N_CONV; ++i) v += pb[i*OUT_DIM + c];
  ball[c] = v;
}

extern "C" void kernel_launch(void* const* d_in, const int* in_sizes, int n_in,
                              void* d_out, int out_size, void* d_ws, size_t ws_size,
                              hipStream_t stream){
  const float* h    = (const float*)d_in[0];
  const float* c0W1 = (const float*)d_in[1];
  const float* cW1  = (const float*)d_in[2];
  const float* cW2  = (const float*)d_in[3];
  const float* bn1g = (const float*)d_in[4];
  const float* bn1b = (const float*)d_in[5];
  const float* bn2g = (const float*)d_in[6];
  const float* bn2b = (const float*)d_in[7];
  const float* p0W  = (const float*)d_in[8];
  const float* p0b  = (const float*)d_in[9];
  const float* pW   = (const float*)d_in[10];
  const float* pb   = (const float*)d_in[11];
  const int* src    = (const int*)d_in[12];
  const int* dst    = (const int*)d_in[13];
  float* out = (float*)d_out;

  char* w = (char*)d_ws;
  auto alloc = [&](size_t bytes)->char*{ char* p = w; w += (bytes + 255) & ~(size_t)255; return p; };
  float* agg    = (float*)alloc((size_t)N_NODES*HID*4);
  float* t      = (float*)alloc((size_t)N_NODES*HID*4);
  float* x      = (float*)alloc((size_t)N_NODES*HID*4);
  int* row_ptr  = (int*)alloc((N_NODES+1)*4);
  int* cursor   = (int*)alloc(N_NODES*4);
  int* counts   = (int*)alloc(N_NODES*4);
  int* esrc     = (int*)alloc(N_EDGES*4);
  float* sums   = (float*)alloc(2*HID*4);
  float* stats  = (float*)alloc(2*HID*4);
  float* ball   = (float*)alloc(OUT_DIM*4);

  // ---- CSR build (by dst) ----
  hipMemsetAsync(counts, 0, N_NODES*4, stream);
  k_count<<<(N_EDGES+255)/256, 256, 0, stream>>>(dst, counts, N_EDGES);
  k_scan<<<1, 1024, 0, stream>>>(counts, row_ptr, N_NODES);
  hipMemcpyAsync(cursor, row_ptr, N_NODES*4, hipMemcpyDeviceToDevice, stream);
  k_fill<<<(N_EDGES+255)/256, 256, 0, stream>>>(src, dst, cursor, esrc, N_EDGES);
  k_biasall<<<1, OUT_DIM, 0, stream>>>(p0b, pb, ball);

  // out = h @ pred0_W + (pred0_b + sum_i preds_b[i])
  k_gemm<1><<<dim3(1, (N_NODES+63)/64), 256, 0, stream>>>(h, p0W, out, ball, N_NODES, OUT_DIM, IN_DIM);

  for (int i = 0; i < N_CONV; ++i){
    int K1 = (i == 0) ? IN_DIM : HID;
    if (i == 0)
      k_aggregate<IN_DIM><<<(N_NODES*64+255)/256, 256, 0, stream>>>(h, row_ptr, esrc, agg, N_NODES);
    else
      k_aggregate<HID><<<(N_NODES*64+255)/256, 256, 0, stream>>>(x, row_ptr, esrc, agg, N_NODES);

    const float* W1 = (i == 0) ? c0W1 : (cW1 + (size_t)(i-1)*HID*HID);
    k_gemm<0><<<dim3(HID/64, (N_NODES+63)/64), 256, 0, stream>>>(agg, W1, t, nullptr, N_NODES, HID, K1);

    hipMemsetAsync(sums, 0, 2*HID*4, stream);
    k_colstats<<<(N_NODES+255)/256, 256, 0, stream>>>(t, sums, N_NODES);
    k_finstats<<<1, HID, 0, stream>>>(sums, stats, N_NODES);
    k_bnrelu<<<(N_NODES*(HID/4)+255)/256, 256, 0, stream>>>(t, stats, bn1g + i*HID, bn1b + i*HID, t, N_NODES);

    k_gemm<0><<<dim3(HID/64, (N_NODES+63)/64), 256, 0, stream>>>(t, cW2 + (size_t)i*HID*HID, agg, nullptr, N_NODES, HID, HID);

    hipMemsetAsync(sums, 0, 2*HID*4, stream);
    k_colstats<<<(N_NODES+255)/256, 256, 0, stream>>>(agg, sums, N_NODES);
    k_finstats<<<1, HID, 0, stream>>>(sums, stats, N_NODES);
    k_bnrelu<<<(N_NODES*(HID/4)+255)/256, 256, 0, stream>>>(agg, stats, bn2g + i*HID, bn2b + i*HID, x, N_NODES);

    // out += x @ preds_W[i]
    k_gemm<2><<<dim3(1, (N_NODES+63)/64), 256, 0, stream>>>(x, pW + (size_t)i*HID*OUT_DIM, out, nullptr, N_NODES, OUT_DIM, HID);
  }
}

// Round 2
// 1015.765 us; speedup vs baseline: 2.1925x; 2.1925x over previous
//
#include <hip/hip_runtime.h>

#define N_NODES 50000
#define MPAD    50176
#define N_EDGES 800000
#define IN_DIM 128
#define HID 256
#define OUT_DIM 64
#define N_CONV 4

typedef __bf16 bf16;
typedef __attribute__((ext_vector_type(8))) __bf16 bf16x8;
typedef __attribute__((ext_vector_type(4))) float f32x4;
typedef __attribute__((ext_vector_type(4))) unsigned short us4;
typedef unsigned short ushort_t;

__device__ __forceinline__ unsigned short f2b(float f){
  unsigned u = __float_as_uint(f);
  u += 0x7fffu + ((u >> 16) & 1u);
  return (unsigned short)(u >> 16);
}
__device__ __forceinline__ float b2f_lo(unsigned v){ return __uint_as_float(v << 16); }
__device__ __forceinline__ float b2f_hi(unsigned v){ return __uint_as_float(v & 0xffff0000u); }

__device__ __forceinline__ void stage16(const void* g, void* l){
  __builtin_amdgcn_global_load_lds((const __attribute__((address_space(1))) unsigned int*)g,
                                   (__attribute__((address_space(3))) unsigned int*)l, 16, 0, 0);
}

// ---------------- CSR build ----------------
__global__ void k_count(const int* __restrict__ dst, int* __restrict__ cnt, int ne){
  int e = blockIdx.x*blockDim.x + threadIdx.x;
  if (e < ne) atomicAdd(&cnt[dst[e]], 1);
}

__global__ void k_scan(const int* __restrict__ cnt, int* __restrict__ row_ptr, int n){
  __shared__ int sd[1024];
  __shared__ int carry;
  if (threadIdx.x == 0) carry = 0;
  __syncthreads();
  for (int base = 0; base < n; base += 1024){
    int i = base + (int)threadIdx.x;
    int v = (i < n) ? cnt[i] : 0;
    sd[threadIdx.x] = v;
    __syncthreads();
    #pragma unroll
    for (int off = 1; off < 1024; off <<= 1){
      int t = (threadIdx.x >= (unsigned)off) ? sd[threadIdx.x - off] : 0;
      __syncthreads();
      sd[threadIdx.x] += t;
      __syncthreads();
    }
    if (i < n) row_ptr[i+1] = carry + sd[threadIdx.x];
    __syncthreads();
    if (threadIdx.x == 1023) carry += sd[1023];
    __syncthreads();
  }
  if (threadIdx.x == 0) row_ptr[0] = 0;
}

__global__ void k_fill(const int* __restrict__ src, const int* __restrict__ dst,
                       int* __restrict__ cursor, int* __restrict__ esrc, int ne){
  int e = blockIdx.x*blockDim.x + threadIdx.x;
  if (e < ne){
    int p = atomicAdd(&cursor[dst[e]], 1);
    esrc[p] = src[e];
  }
}

// ---------------- aggregation (bf16 in/out, fp32 accum) ----------------
template<int D>
__global__ void k_agg(const ushort_t* __restrict__ x, const int* __restrict__ rp,
                      const int* __restrict__ es, ushort_t* __restrict__ agg, int n){
  int gw = (int)((blockIdx.x*(size_t)blockDim.x + threadIdx.x) >> 6);
  int lane = threadIdx.x & 63;
  if (gw >= n) return;
  if (D == 256){
    uint2 v = *(const uint2*)(x + (size_t)gw*D + lane*4);
    float a0 = b2f_lo(v.x), a1 = b2f_hi(v.x), a2 = b2f_lo(v.y), a3 = b2f_hi(v.y);
    int e1 = rp[gw+1];
    for (int e = rp[gw]; e < e1; ++e){
      int s = es[e];
      uint2 w = *(const uint2*)(x + (size_t)s*D + lane*4);
      a0 += b2f_lo(w.x); a1 += b2f_hi(w.x); a2 += b2f_lo(w.y); a3 += b2f_hi(w.y);
    }
    us4 o; o.x = f2b(a0); o.y = f2b(a1); o.z = f2b(a2); o.w = f2b(a3);
    *(us4*)(agg + (size_t)gw*D + lane*4) = o;
  } else {
    unsigned v = *(const unsigned*)(x + (size_t)gw*D + lane*2);
    float a0 = b2f_lo(v), a1 = b2f_hi(v);
    int e1 = rp[gw+1];
    for (int e = rp[gw]; e < e1; ++e){
      int s = es[e];
      unsigned w = *(const unsigned*)(x + (size_t)s*D + lane*2);
      a0 += b2f_lo(w); a1 += b2f_hi(w);
    }
    unsigned o = (unsigned)f2b(a0) | ((unsigned)f2b(a1) << 16);
    *(unsigned*)(agg + (size_t)gw*D + lane*2) = o;
  }
}

// ---------------- BN finalize + BN-ReLU (fp32 in, bf16 out) ----------------
__global__ void k_finstats(const float* __restrict__ sums, float* __restrict__ stats, int M){
  int c = threadIdx.x;
  float mean = sums[c] / (float)M;
  float var  = sums[HID + c] / (float)M - mean*mean;
  stats[c] = mean;
  stats[HID + c] = rsqrtf(var + 1e-5f);
}

__global__ void k_bnrelu(const float* __restrict__ t, const float* __restrict__ st,
                         const float* __restrict__ g, const float* __restrict__ b,
                         ushort_t* __restrict__ o, int M){
  int idx = blockIdx.x*blockDim.x + threadIdx.x;
  if (idx >= M*(HID/4)) return;
  int cg = (idx & 63) * 4;
  float4 v = *(const float4*)(t + (size_t)idx*4);
  float vv[4] = {v.x, v.y, v.z, v.w};
  unsigned short r[4];
  #pragma unroll
  for (int j = 0; j < 4; ++j){
    int c = cg + j;
    float y = (vv[j] - st[c]) * st[HID + c] * g[c] + b[c];
    r[j] = f2b(y > 0.f ? y : 0.f);
  }
  us4 o4; o4.x = r[0]; o4.y = r[1]; o4.z = r[2]; o4.w = r[3];
  *(us4*)(o + (size_t)idx*4) = o4;
}

// ---------------- fp32 -> bf16 bulk convert ----------------
__global__ void k_f2b(const float* __restrict__ in, ushort_t* __restrict__ out, int n4){
  int i = blockIdx.x*blockDim.x + threadIdx.x;
  if (i >= n4) return;
  float4 v = *(const float4*)(in + (size_t)i*4);
  us4 o; o.x = f2b(v.x); o.y = f2b(v.y); o.z = f2b(v.z); o.w = f2b(v.w);
  *(us4*)(out + (size_t)i*4) = o;
}

// ---------------- weight transpose + convert (fp32 [R][C] -> bf16 [C][R]) ----------------
__global__ void k_wprep(const float* __restrict__ c0W1, const float* __restrict__ cW1,
                        const float* __restrict__ cW2, const float* __restrict__ p0W,
                        const float* __restrict__ pW, ushort_t* __restrict__ wb){
  int m = blockIdx.y;
  const float* src; int R, C; ushort_t* dst;
  if (m == 0){       src = c0W1;                R = 128; C = 256; dst = wb; }
  else if (m <= 3){  src = cW1 + (m-1)*65536;   R = 256; C = 256; dst = wb + 32768 + (m-1)*65536; }
  else if (m <= 7){  src = cW2 + (m-4)*65536;   R = 256; C = 256; dst = wb + 229376 + (m-4)*65536; }
  else if (m == 8){  src = p0W;                 R = 128; C = 64;  dst = wb + 491520; }
  else {             src = pW + (m-9)*16384;    R = 256; C = 64;  dst = wb + 499712 + (m-9)*16384; }
  int tx = R/64, tiles = tx * (C/64);
  int t = blockIdx.x;
  if (t >= tiles) return;
  int sr0 = (t % tx)*64, sc0 = (t / tx)*64;
  __shared__ float ld[64][65];
  int c = threadIdx.x & 63, rq = threadIdx.x >> 6;
  #pragma unroll
  for (int i = 0; i < 16; ++i){
    int rr = i*4 + rq;
    ld[rr][c] = src[(size_t)(sr0+rr)*C + sc0 + c];
  }
  __syncthreads();
  #pragma unroll
  for (int i = 0; i < 16; ++i){
    int rr = i*4 + rq;
    dst[(size_t)(sc0+rr)*R + sr0 + c] = f2b(ld[c][rr]);
  }
}

__global__ void k_biasall(const float* __restrict__ p0b, const float* __restrict__ pb,
                          float* __restrict__ ball){
  int c = threadIdx.x;
  float v = p0b[c];
  #pragma unroll
  for (int i = 0; i < N_CONV; ++i) v += pb[i*OUT_DIM + c];
  ball[c] = v;
}

// ---------------- MFMA GEMM: C[M,N] = A[M,K](bf16) @ BT[N,K](bf16)^T ----------------
// MODE 0: store fp32 + fused column sum/sumsq into sums[0..N)/[256..256+N)
// MODE 1: store fp32 + bias[col] (masked row<M)
// MODE 2: accumulate fp32 into C (masked row<M)
template<int BM, int BN, int MODE>
__global__ __launch_bounds__((BM/64)*(BN/64)*64)
void k_mgemm(const bf16* __restrict__ A, const bf16* __restrict__ BT,
             float* __restrict__ C, const float* __restrict__ bias,
             float* __restrict__ sums, int M, int N, int K)
{
  constexpr int NW  = (BM/64)*(BN/64);
  constexpr int WNT = BN/64;
  constexpr int ACH = BM/16, BCH = BN/16;
  __shared__ __align__(16) bf16 As[BM*32];
  __shared__ __align__(16) bf16 Bs[BN*32];
  const int tid = threadIdx.x;
  const int wid = tid >> 6, l = tid & 63;
  const int wm = wid / WNT, wn = wid % WNT;
  const int m0 = blockIdx.y * BM, n0 = blockIdx.x * BN;
  const int r = l & 15, q = l >> 4;
  const int fragByte = ((q ^ ((r >> 1) & 3)) << 4);     // reader granule swizzle
  const int wrow = l >> 2;                              // staging: row within 16-row chunk
  const int wk = (((l & 3) ^ ((l >> 3) & 3)) << 3);     // staging: pre-swizzled k element offset
  f32x4 acc[4][4] = {};
  for (int k0 = 0; k0 < K; k0 += 32){
    __syncthreads();
    #pragma unroll
    for (int c = 0; c < ACH/NW; ++c){
      int ch = wid + c*NW;
      const bf16* g = A + (size_t)(m0 + ch*16 + wrow)*K + (k0 + wk);
      stage16(g, (char*)As + ch*1024);
    }
    #pragma unroll
    for (int c = 0; c < BCH/NW; ++c){
      int ch = wid + c*NW;
      const bf16* g = BT + (size_t)(n0 + ch*16 + wrow)*K + (k0 + wk);
      stage16(g, (char*)Bs + ch*1024);
    }
    __syncthreads();
    bf16x8 af[4], bfr[4];
    #pragma unroll
    for (int mf = 0; mf < 4; ++mf)
      af[mf] = *(const bf16x8*)((const char*)As + (wm*64 + mf*16 + r)*64 + fragByte);
    #pragma unroll
    for (int nf = 0; nf < 4; ++nf)
      bfr[nf] = *(const bf16x8*)((const char*)Bs + (wn*64 + nf*16 + r)*64 + fragByte);
    #pragma unroll
    for (int mf = 0; mf < 4; ++mf)
      #pragma unroll
      for (int nf = 0; nf < 4; ++nf)
        acc[mf][nf] = __builtin_amdgcn_mfma_f32_16x16x32_bf16(af[mf], bfr[nf], acc[mf][nf], 0, 0, 0);
  }

  if (MODE == 0){
    // fused column stats (zero-padded A rows contribute 0 — exact)
    #pragma unroll
    for (int nf = 0; nf < 4; ++nf){
      float s1 = 0.f, s2 = 0.f;
      #pragma unroll
      for (int mf = 0; mf < 4; ++mf)
        #pragma unroll
        for (int j = 0; j < 4; ++j){
          float v = acc[mf][nf][j];
          s1 += v; s2 = fmaf(v, v, s2);
        }
      s1 += __shfl_xor(s1, 16, 64); s1 += __shfl_xor(s1, 32, 64);
      s2 += __shfl_xor(s2, 16, 64); s2 += __shfl_xor(s2, 32, 64);
      if (q == 0){
        int col = n0 + wn*64 + nf*16 + r;
        atomicAdd(&sums[col], s1);
        atomicAdd(&sums[256 + col], s2);
      }
    }
  }
  #pragma unroll
  for (int mf = 0; mf < 4; ++mf){
    #pragma unroll
    for (int j = 0; j < 4; ++j){
      int row = m0 + wm*64 + mf*16 + q*4 + j;
      if (MODE != 0 && row >= M) continue;
      #pragma unroll
      for (int nf = 0; nf < 4; ++nf){
        int col = n0 + wn*64 + nf*16 + r;
        if (MODE == 0)      C[(size_t)row*N + col] = acc[mf][nf][j];
        else if (MODE == 1) C[(size_t)row*N + col] = acc[mf][nf][j] + bias[col];
        else                C[(size_t)row*N + col] += acc[mf][nf][j];
      }
    }
  }
}

extern "C" void kernel_launch(void* const* d_in, const int* in_sizes, int n_in,
                              void* d_out, int out_size, void* d_ws, size_t ws_size,
                              hipStream_t stream){
  const float* h    = (const float*)d_in[0];
  const float* c0W1 = (const float*)d_in[1];
  const float* cW1  = (const float*)d_in[2];
  const float* cW2  = (const float*)d_in[3];
  const float* bn1g = (const float*)d_in[4];
  const float* bn1b = (const float*)d_in[5];
  const float* bn2g = (const float*)d_in[6];
  const float* bn2b = (const float*)d_in[7];
  const float* p0W  = (const float*)d_in[8];
  const float* p0b  = (const float*)d_in[9];
  const float* pW   = (const float*)d_in[10];
  const float* pb   = (const float*)d_in[11];
  const int* src    = (const int*)d_in[12];
  const int* dst    = (const int*)d_in[13];
  float* out = (float*)d_out;

  char* w = (char*)d_ws;
  auto alloc = [&](size_t bytes)->char*{ char* p = w; w += (bytes + 255) & ~(size_t)255; return p; };
  float*    t    = (float*)alloc((size_t)MPAD*HID*4);
  ushort_t* hb   = (ushort_t*)alloc((size_t)MPAD*IN_DIM*2);
  ushort_t* aggb = (ushort_t*)alloc((size_t)MPAD*HID*2);
  ushort_t* tb   = (ushort_t*)alloc((size_t)MPAD*HID*2);
  ushort_t* xb   = (ushort_t*)alloc((size_t)MPAD*HID*2);
  ushort_t* wb   = (ushort_t*)alloc((size_t)565248*2);
  int* row_ptr   = (int*)alloc((N_NODES+1)*4);
  int* cursor    = (int*)alloc(N_NODES*4);
  int* counts    = (int*)alloc(N_NODES*4);
  int* esrc      = (int*)alloc(N_EDGES*4);
  float* sums    = (float*)alloc(2*HID*4);
  float* stats   = (float*)alloc(2*HID*4);
  float* ball    = (float*)alloc(OUT_DIM*4);

  const int PADR = MPAD - N_NODES;  // 176
  // zero the padded tails (makes OOB staging reads exact zeros for fused stats)
  hipMemsetAsync(hb   + (size_t)N_NODES*IN_DIM, 0, (size_t)PADR*IN_DIM*2, stream);
  hipMemsetAsync(aggb + (size_t)N_NODES*IN_DIM, 0, (size_t)PADR*IN_DIM*2, stream); // stride-128 view (layer 0)
  hipMemsetAsync(aggb + (size_t)N_NODES*HID,    0, (size_t)PADR*HID*2,    stream); // stride-256 view
  hipMemsetAsync(tb   + (size_t)N_NODES*HID,    0, (size_t)PADR*HID*2,    stream);
  hipMemsetAsync(xb   + (size_t)N_NODES*HID,    0, (size_t)PADR*HID*2,    stream);

  // ---- CSR build (by dst) ----
  hipMemsetAsync(counts, 0, N_NODES*4, stream);
  k_count<<<(N_EDGES+255)/256, 256, 0, stream>>>(dst, counts, N_EDGES);
  k_scan<<<1, 1024, 0, stream>>>(counts, row_ptr, N_NODES);
  hipMemcpyAsync(cursor, row_ptr, N_NODES*4, hipMemcpyDeviceToDevice, stream);
  k_fill<<<(N_EDGES+255)/256, 256, 0, stream>>>(src, dst, cursor, esrc, N_EDGES);

  // ---- weight prep + h->bf16 + fused bias ----
  k_wprep<<<dim3(16, 13), 256, 0, stream>>>(c0W1, cW1, cW2, p0W, pW, wb);
  k_f2b<<<(N_NODES*IN_DIM/4 + 255)/256, 256, 0, stream>>>(h, hb, N_NODES*IN_DIM/4);
  k_biasall<<<1, OUT_DIM, 0, stream>>>(p0b, pb, ball);

  const ushort_t* pWT0 = wb + 491520;
  // out = h @ pred0_W + (pred0_b + sum_i preds_b[i])
  k_mgemm<128, 64, 1><<<dim3(1, MPAD/128), 128, 0, stream>>>(
      (const bf16*)hb, (const bf16*)pWT0, out, ball, nullptr, N_NODES, OUT_DIM, IN_DIM);

  for (int i = 0; i < N_CONV; ++i){
    int K1 = (i == 0) ? IN_DIM : HID;
    if (i == 0)
      k_agg<IN_DIM><<<(N_NODES*64+255)/256, 256, 0, stream>>>(hb, row_ptr, esrc, aggb, N_NODES);
    else
      k_agg<HID><<<(N_NODES*64+255)/256, 256, 0, stream>>>(xb, row_ptr, esrc, aggb, N_NODES);

    const ushort_t* W1T = (i == 0) ? wb : (wb + 32768 + (size_t)(i-1)*65536);
    hipMemsetAsync(sums, 0, 2*HID*4, stream);
    k_mgemm<128, 128, 0><<<dim3(2, MPAD/128), 256, 0, stream>>>(
        (const bf16*)aggb, (const bf16*)W1T, t, nullptr, sums, N_NODES, HID, K1);
    k_finstats<<<1, HID, 0, stream>>>(sums, stats, N_NODES);
    k_bnrelu<<<(N_NODES*(HID/4)+255)/256, 256, 0, stream>>>(t, stats, bn1g + i*HID, bn1b + i*HID, tb, N_NODES);

    const ushort_t* W2T = wb + 229376 + (size_t)i*65536;
    hipMemsetAsync(sums, 0, 2*HID*4, stream);
    k_mgemm<128, 128, 0><<<dim3(2, MPAD/128), 256, 0, stream>>>(
        (const bf16*)tb, (const bf16*)W2T, t, nullptr, sums, N_NODES, HID, HID);
    k_finstats<<<1, HID, 0, stream>>>(sums, stats, N_NODES);
    k_bnrelu<<<(N_NODES*(HID/4)+255)/256, 256, 0, stream>>>(t, stats, bn2g + i*HID, bn2b + i*HID, xb, N_NODES);

    const ushort_t* pWT = wb + 499712 + (size_t)i*16384;
    k_mgemm<128, 64, 2><<<dim3(1, MPAD/128), 128, 0, stream>>>(
        (const bf16*)xb, (const bf16*)pWT, out, nullptr, nullptr, N_NODES, OUT_DIM, HID);
  }
}

// Round 3
// 786.390 us; speedup vs baseline: 2.8320x; 1.2917x over previous
//
#include <hip/hip_runtime.h>

#define N_NODES 50000
#define MPAD    50176
#define N_EDGES 800000
#define IN_DIM 128
#define HID 256
#define OUT_DIM 64
#define N_CONV 4

typedef __bf16 bf16;
typedef __attribute__((ext_vector_type(8))) __bf16 bf16x8;
typedef __attribute__((ext_vector_type(4))) float f32x4;
typedef __attribute__((ext_vector_type(4))) unsigned short us4;
typedef unsigned short ushort_t;

__device__ __forceinline__ unsigned short f2b(float f){
  unsigned u = __float_as_uint(f);
  u += 0x7fffu + ((u >> 16) & 1u);
  return (unsigned short)(u >> 16);
}
__device__ __forceinline__ float b2f_lo(unsigned v){ return __uint_as_float(v << 16); }
__device__ __forceinline__ float b2f_hi(unsigned v){ return __uint_as_float(v & 0xffff0000u); }

__device__ __forceinline__ void stage16(const void* g, void* l){
  __builtin_amdgcn_global_load_lds((const __attribute__((address_space(1))) unsigned int*)g,
                                   (__attribute__((address_space(3))) unsigned int*)l, 16, 0, 0);
}

// ---------------- CSR build ----------------
__global__ void k_count(const int* __restrict__ dst, int* __restrict__ cnt, int ne){
  int e = blockIdx.x*blockDim.x + threadIdx.x;
  if (e < ne) atomicAdd(&cnt[dst[e]], 1);
}

// parallel scan, pass 1: per-block (256) inclusive scan + block sums
__global__ void k_scan1(const int* __restrict__ cnt, int* __restrict__ scanned,
                        int* __restrict__ bsum, int n){
  int i = blockIdx.x*256 + threadIdx.x;
  int v = (i < n) ? cnt[i] : 0;
  int lane = threadIdx.x & 63;
  #pragma unroll
  for (int off = 1; off < 64; off <<= 1){
    int t = __shfl_up(v, off, 64);
    if (lane >= off) v += t;
  }
  __shared__ int wsum[4];
  int wv = threadIdx.x >> 6;
  if (lane == 63) wsum[wv] = v;
  __syncthreads();
  if (threadIdx.x == 0){
    int s = 0;
    #pragma unroll
    for (int k = 0; k < 4; ++k){ int t = wsum[k]; wsum[k] = s; s += t; }
    bsum[blockIdx.x] = s;
  }
  __syncthreads();
  v += wsum[wv];
  if (i < n) scanned[i] = v;
}

// pass 2: inclusive scan of block sums (nb <= 256) in one block
__global__ void k_scan2(int* __restrict__ bsum, int nb){
  __shared__ int sd[256];
  int i = threadIdx.x;
  sd[i] = (i < nb) ? bsum[i] : 0;
  __syncthreads();
  #pragma unroll
  for (int off = 1; off < 256; off <<= 1){
    int t = (i >= off) ? sd[i-off] : 0;
    __syncthreads();
    sd[i] += t;
    __syncthreads();
  }
  if (i < nb) bsum[i] = sd[i];
}

// pass 3: row_ptr[i+1] = global inclusive; cursor[i] = global exclusive
__global__ void k_scan3(const int* __restrict__ scanned, const int* __restrict__ bsum,
                        const int* __restrict__ cnt, int* __restrict__ row_ptr,
                        int* __restrict__ cursor, int n){
  int i = blockIdx.x*256 + threadIdx.x;
  if (i < n){
    int off = (blockIdx.x > 0) ? bsum[blockIdx.x-1] : 0;
    int inc = scanned[i] + off;
    row_ptr[i+1] = inc;
    cursor[i] = inc - cnt[i];
  }
  if (i == 0) row_ptr[0] = 0;
}

__global__ void k_fill(const int* __restrict__ src, const int* __restrict__ dst,
                       int* __restrict__ cursor, int* __restrict__ esrc, int ne){
  int e = blockIdx.x*blockDim.x + threadIdx.x;
  if (e < ne){
    int p = atomicAdd(&cursor[dst[e]], 1);
    esrc[p] = src[e];
  }
}

// ---------------- aggregation (bf16 in/out, fp32 accum, 4x MLP unroll) ----------------
template<int D>
__global__ void k_agg(const ushort_t* __restrict__ x, const int* __restrict__ rp,
                      const int* __restrict__ es, ushort_t* __restrict__ agg, int n){
  int gw = (int)((blockIdx.x*(size_t)blockDim.x + threadIdx.x) >> 6);
  int lane = threadIdx.x & 63;
  if (gw >= n) return;
  if (D == 256){
    const uint2* xp = (const uint2*)x;   // row stride = 64 uint2
    uint2 v = xp[(size_t)gw*64 + lane];
    float a0 = b2f_lo(v.x), a1 = b2f_hi(v.x), a2 = b2f_lo(v.y), a3 = b2f_hi(v.y);
    float c0 = 0.f, c1 = 0.f, c2 = 0.f, c3 = 0.f;
    int e = rp[gw], e1 = rp[gw+1];
    for (; e + 4 <= e1; e += 4){
      int s0 = es[e], s1 = es[e+1], s2 = es[e+2], s3 = es[e+3];
      uint2 w0 = xp[(size_t)s0*64 + lane];
      uint2 w1 = xp[(size_t)s1*64 + lane];
      uint2 w2 = xp[(size_t)s2*64 + lane];
      uint2 w3 = xp[(size_t)s3*64 + lane];
      a0 += b2f_lo(w0.x); a1 += b2f_hi(w0.x); a2 += b2f_lo(w0.y); a3 += b2f_hi(w0.y);
      c0 += b2f_lo(w1.x); c1 += b2f_hi(w1.x); c2 += b2f_lo(w1.y); c3 += b2f_hi(w1.y);
      a0 += b2f_lo(w2.x); a1 += b2f_hi(w2.x); a2 += b2f_lo(w2.y); a3 += b2f_hi(w2.y);
      c0 += b2f_lo(w3.x); c1 += b2f_hi(w3.x); c2 += b2f_lo(w3.y); c3 += b2f_hi(w3.y);
    }
    for (; e < e1; ++e){
      int s = es[e];
      uint2 w = xp[(size_t)s*64 + lane];
      a0 += b2f_lo(w.x); a1 += b2f_hi(w.x); a2 += b2f_lo(w.y); a3 += b2f_hi(w.y);
    }
    a0 += c0; a1 += c1; a2 += c2; a3 += c3;
    us4 o; o.x = f2b(a0); o.y = f2b(a1); o.z = f2b(a2); o.w = f2b(a3);
    *(us4*)(agg + (size_t)gw*D + lane*4) = o;
  } else {
    const unsigned* xp = (const unsigned*)x;  // row stride = 64 uints
    unsigned v = xp[(size_t)gw*64 + lane];
    float a0 = b2f_lo(v), a1 = b2f_hi(v);
    float c0 = 0.f, c1 = 0.f;
    int e = rp[gw], e1 = rp[gw+1];
    for (; e + 4 <= e1; e += 4){
      int s0 = es[e], s1 = es[e+1], s2 = es[e+2], s3 = es[e+3];
      unsigned w0 = xp[(size_t)s0*64 + lane];
      unsigned w1 = xp[(size_t)s1*64 + lane];
      unsigned w2 = xp[(size_t)s2*64 + lane];
      unsigned w3 = xp[(size_t)s3*64 + lane];
      a0 += b2f_lo(w0); a1 += b2f_hi(w0);
      c0 += b2f_lo(w1); c1 += b2f_hi(w1);
      a0 += b2f_lo(w2); a1 += b2f_hi(w2);
      c0 += b2f_lo(w3); c1 += b2f_hi(w3);
    }
    for (; e < e1; ++e){
      int s = es[e];
      unsigned w = xp[(size_t)s*64 + lane];
      a0 += b2f_lo(w); a1 += b2f_hi(w);
    }
    a0 += c0; a1 += c1;
    unsigned o = (unsigned)f2b(a0) | ((unsigned)f2b(a1) << 16);
    *(unsigned*)(agg + (size_t)gw*D + lane*2) = o;
  }
}

// ---------------- BN+ReLU (fp32 in, bf16 out, inline stats from sums) ----------------
__global__ void k_bnrelu(const float* __restrict__ t, const float* __restrict__ sums,
                         const float* __restrict__ g, const float* __restrict__ b,
                         ushort_t* __restrict__ o, int M, float invM){
  int idx = blockIdx.x*blockDim.x + threadIdx.x;
  if (idx >= M*(HID/4)) return;
  int cg = (idx & 63) * 4;
  float4 v = *(const float4*)(t + (size_t)idx*4);
  float vv[4] = {v.x, v.y, v.z, v.w};
  unsigned short r[4];
  #pragma unroll
  for (int j = 0; j < 4; ++j){
    int c = cg + j;
    float mean = sums[c] * invM;
    float var  = sums[HID + c] * invM - mean*mean;
    float rsq  = rsqrtf(var + 1e-5f);
    float y = (vv[j] - mean) * rsq * g[c] + b[c];
    r[j] = f2b(y > 0.f ? y : 0.f);
  }
  us4 o4; o4.x = r[0]; o4.y = r[1]; o4.z = r[2]; o4.w = r[3];
  *(us4*)(o + (size_t)idx*4) = o4;
}

// ---------------- fp32 -> bf16 bulk convert ----------------
__global__ void k_f2b(const float* __restrict__ in, ushort_t* __restrict__ out, int n4){
  int i = blockIdx.x*blockDim.x + threadIdx.x;
  if (i >= n4) return;
  float4 v = *(const float4*)(in + (size_t)i*4);
  us4 o; o.x = f2b(v.x); o.y = f2b(v.y); o.z = f2b(v.z); o.w = f2b(v.w);
  *(us4*)(out + (size_t)i*4) = o;
}

// ---------------- weight transpose + convert (fp32 [R][C] -> bf16 [C][R]) ----------------
__global__ void k_wprep(const float* __restrict__ c0W1, const float* __restrict__ cW1,
                        const float* __restrict__ cW2, const float* __restrict__ p0W,
                        const float* __restrict__ pW, ushort_t* __restrict__ wb){
  int m = blockIdx.y;
  const float* src; int R, C; ushort_t* dst;
  if (m == 0){       src = c0W1;                R = 128; C = 256; dst = wb; }
  else if (m <= 3){  src = cW1 + (m-1)*65536;   R = 256; C = 256; dst = wb + 32768 + (m-1)*65536; }
  else if (m <= 7){  src = cW2 + (m-4)*65536;   R = 256; C = 256; dst = wb + 229376 + (m-4)*65536; }
  else if (m == 8){  src = p0W;                 R = 128; C = 64;  dst = wb + 491520; }
  else {             src = pW + (m-9)*16384;    R = 256; C = 64;  dst = wb + 499712 + (m-9)*16384; }
  int tx = R/64, tiles = tx * (C/64);
  int t = blockIdx.x;
  if (t >= tiles) return;
  int sr0 = (t % tx)*64, sc0 = (t / tx)*64;
  __shared__ float ld[64][65];
  int c = threadIdx.x & 63, rq = threadIdx.x >> 6;
  #pragma unroll
  for (int i = 0; i < 16; ++i){
    int rr = i*4 + rq;
    ld[rr][c] = src[(size_t)(sr0+rr)*C + sc0 + c];
  }
  __syncthreads();
  #pragma unroll
  for (int i = 0; i < 16; ++i){
    int rr = i*4 + rq;
    dst[(size_t)(sc0+rr)*R + sr0 + c] = f2b(ld[c][rr]);
  }
}

__global__ void k_biasall(const float* __restrict__ p0b, const float* __restrict__ pb,
                          float* __restrict__ ball){
  int c = threadIdx.x;
  float v = p0b[c];
  #pragma unroll
  for (int i = 0; i < N_CONV; ++i) v += pb[i*OUT_DIM + c];
  ball[c] = v;
}

// ---------------- MFMA GEMM: C[M,N] = A[M,K](bf16) @ BT[N,K](bf16)^T ----------------
// Double-buffered LDS, one barrier per K-tile, staging issued before compute.
// MODE 0: store fp32 + fused column sum/sumsq into sums
// MODE 1: store fp32 + bias[col] (masked row<M)
// MODE 2: accumulate fp32 into C (masked row<M)
template<int BM, int BN, int MODE>
__global__ __launch_bounds__((BM/64)*(BN/64)*64)
void k_mgemm(const bf16* __restrict__ A, const bf16* __restrict__ BT,
             float* __restrict__ C, const float* __restrict__ bias,
             float* __restrict__ sums, int M, int N, int K)
{
  constexpr int NW  = (BM/64)*(BN/64);
  constexpr int WNT = BN/64;
  constexpr int ACH = BM/16, BCH = BN/16;
  __shared__ __align__(16) bf16 As[2*BM*32];
  __shared__ __align__(16) bf16 Bs[2*BN*32];
  const int tid = threadIdx.x;
  const int wid = tid >> 6, l = tid & 63;
  const int wm = wid / WNT, wn = wid % WNT;
  const int m0 = blockIdx.y * BM, n0 = blockIdx.x * BN;
  const int r = l & 15, q = l >> 4;
  const int fragByte = ((q ^ ((r >> 1) & 3)) << 4);     // reader granule swizzle
  const int wrow = l >> 2;                              // staging: row within 16-row chunk
  const int wk = (((l & 3) ^ ((l >> 3) & 3)) << 3);     // staging: pre-swizzled k element offset

  auto STAGE = [&](int buf, int k0){
    #pragma unroll
    for (int c = 0; c < ACH/NW; ++c){
      int ch = wid + c*NW;
      const bf16* g = A + (size_t)(m0 + ch*16 + wrow)*K + (k0 + wk);
      stage16(g, (char*)As + buf*(BM*64) + ch*1024);
    }
    #pragma unroll
    for (int c = 0; c < BCH/NW; ++c){
      int ch = wid + c*NW;
      const bf16* g = BT + (size_t)(n0 + ch*16 + wrow)*K + (k0 + wk);
      stage16(g, (char*)Bs + buf*(BN*64) + ch*1024);
    }
  };

  f32x4 acc[4][4] = {};
  const int nt = K >> 5;
  STAGE(0, 0);
  for (int t = 0; t < nt; ++t){
    int cur = t & 1;
    __syncthreads();                       // drains vmcnt: buf[cur] staged; prev reads done
    if (t + 1 < nt) STAGE(cur ^ 1, (t + 1) << 5);
    bf16x8 af[4], bfr[4];
    #pragma unroll
    for (int mf = 0; mf < 4; ++mf)
      af[mf] = *(const bf16x8*)((const char*)As + cur*(BM*64) + (wm*64 + mf*16 + r)*64 + fragByte);
    #pragma unroll
    for (int nf = 0; nf < 4; ++nf)
      bfr[nf] = *(const bf16x8*)((const char*)Bs + cur*(BN*64) + (wn*64 + nf*16 + r)*64 + fragByte);
    #pragma unroll
    for (int mf = 0; mf < 4; ++mf)
      #pragma unroll
      for (int nf = 0; nf < 4; ++nf)
        acc[mf][nf] = __builtin_amdgcn_mfma_f32_16x16x32_bf16(af[mf], bfr[nf], acc[mf][nf], 0, 0, 0);
  }

  if (MODE == 0){
    #pragma unroll
    for (int nf = 0; nf < 4; ++nf){
      float s1 = 0.f, s2 = 0.f;
      #pragma unroll
      for (int mf = 0; mf < 4; ++mf)
        #pragma unroll
        for (int j = 0; j < 4; ++j){
          float v = acc[mf][nf][j];
          s1 += v; s2 = fmaf(v, v, s2);
        }
      s1 += __shfl_xor(s1, 16, 64); s1 += __shfl_xor(s1, 32, 64);
      s2 += __shfl_xor(s2, 16, 64); s2 += __shfl_xor(s2, 32, 64);
      if (q == 0){
        int col = n0 + wn*64 + nf*16 + r;
        atomicAdd(&sums[col], s1);
        atomicAdd(&sums[256 + col], s2);
      }
    }
  }
  #pragma unroll
  for (int mf = 0; mf < 4; ++mf){
    #pragma unroll
    for (int j = 0; j < 4; ++j){
      int row = m0 + wm*64 + mf*16 + q*4 + j;
      if (MODE != 0 && row >= M) continue;
      #pragma unroll
      for (int nf = 0; nf < 4; ++nf){
        int col = n0 + wn*64 + nf*16 + r;
        if (MODE == 0)      C[(size_t)row*N + col] = acc[mf][nf][j];
        else if (MODE == 1) C[(size_t)row*N + col] = acc[mf][nf][j] + bias[col];
        else                C[(size_t)row*N + col] += acc[mf][nf][j];
      }
    }
  }
}

extern "C" void kernel_launch(void* const* d_in, const int* in_sizes, int n_in,
                              void* d_out, int out_size, void* d_ws, size_t ws_size,
                              hipStream_t stream){
  const float* h    = (const float*)d_in[0];
  const float* c0W1 = (const float*)d_in[1];
  const float* cW1  = (const float*)d_in[2];
  const float* cW2  = (const float*)d_in[3];
  const float* bn1g = (const float*)d_in[4];
  const float* bn1b = (const float*)d_in[5];
  const float* bn2g = (const float*)d_in[6];
  const float* bn2b = (const float*)d_in[7];
  const float* p0W  = (const float*)d_in[8];
  const float* p0b  = (const float*)d_in[9];
  const float* pW   = (const float*)d_in[10];
  const float* pb   = (const float*)d_in[11];
  const int* src    = (const int*)d_in[12];
  const int* dst    = (const int*)d_in[13];
  float* out = (float*)d_out;

  char* w = (char*)d_ws;
  auto alloc = [&](size_t bytes)->char*{ char* p = w; w += (bytes + 255) & ~(size_t)255; return p; };
  float*    t    = (float*)alloc((size_t)MPAD*HID*4);
  ushort_t* hb   = (ushort_t*)alloc((size_t)MPAD*IN_DIM*2);
  ushort_t* aggb = (ushort_t*)alloc((size_t)MPAD*HID*2);
  ushort_t* tb   = (ushort_t*)alloc((size_t)MPAD*HID*2);
  ushort_t* xb   = (ushort_t*)alloc((size_t)MPAD*HID*2);
  ushort_t* wb   = (ushort_t*)alloc((size_t)565248*2);
  int* row_ptr   = (int*)alloc((N_NODES+1)*4);
  int* cursor    = (int*)alloc(N_NODES*4);
  int* counts    = (int*)alloc(N_NODES*4);
  int* esrc      = (int*)alloc(N_EDGES*4);
  int* scanned   = (int*)alloc(N_NODES*4);
  int* bsum      = (int*)alloc(256*4);
  float* sums    = (float*)alloc(2*HID*4);
  float* ball    = (float*)alloc(OUT_DIM*4);

  const int PADR = MPAD - N_NODES;  // 176
  hipMemsetAsync(hb   + (size_t)N_NODES*IN_DIM, 0, (size_t)PADR*IN_DIM*2, stream);
  hipMemsetAsync(aggb + (size_t)N_NODES*IN_DIM, 0, (size_t)PADR*IN_DIM*2, stream);
  hipMemsetAsync(aggb + (size_t)N_NODES*HID,    0, (size_t)PADR*HID*2,    stream);
  hipMemsetAsync(tb   + (size_t)N_NODES*HID,    0, (size_t)PADR*HID*2,    stream);
  hipMemsetAsync(xb   + (size_t)N_NODES*HID,    0, (size_t)PADR*HID*2,    stream);

  // ---- CSR build (by dst) ----
  const int NB = (N_NODES + 255) / 256;  // 196
  hipMemsetAsync(counts, 0, N_NODES*4, stream);
  k_count<<<(N_EDGES+255)/256, 256, 0, stream>>>(dst, counts, N_EDGES);
  k_scan1<<<NB, 256, 0, stream>>>(counts, scanned, bsum, N_NODES);
  k_scan2<<<1, 256, 0, stream>>>(bsum, NB);
  k_scan3<<<NB, 256, 0, stream>>>(scanned, bsum, counts, row_ptr, cursor, N_NODES);
  k_fill<<<(N_EDGES+255)/256, 256, 0, stream>>>(src, dst, cursor, esrc, N_EDGES);

  // ---- weight prep + h->bf16 + fused bias ----
  k_wprep<<<dim3(16, 13), 256, 0, stream>>>(c0W1, cW1, cW2, p0W, pW, wb);
  k_f2b<<<(N_NODES*IN_DIM/4 + 255)/256, 256, 0, stream>>>(h, hb, N_NODES*IN_DIM/4);
  k_biasall<<<1, OUT_DIM, 0, stream>>>(p0b, pb, ball);

  const ushort_t* pWT0 = wb + 491520;
  k_mgemm<128, 64, 1><<<dim3(1, MPAD/128), 128, 0, stream>>>(
      (const bf16*)hb, (const bf16*)pWT0, out, ball, nullptr, N_NODES, OUT_DIM, IN_DIM);

  const float invM = 1.0f / (float)N_NODES;
  for (int i = 0; i < N_CONV; ++i){
    int K1 = (i == 0) ? IN_DIM : HID;
    if (i == 0)
      k_agg<IN_DIM><<<(N_NODES*64+255)/256, 256, 0, stream>>>(hb, row_ptr, esrc, aggb, N_NODES);
    else
      k_agg<HID><<<(N_NODES*64+255)/256, 256, 0, stream>>>(xb, row_ptr, esrc, aggb, N_NODES);

    const ushort_t* W1T = (i == 0) ? wb : (wb + 32768 + (size_t)(i-1)*65536);
    hipMemsetAsync(sums, 0, 2*HID*4, stream);
    k_mgemm<128, 128, 0><<<dim3(2, MPAD/128), 256, 0, stream>>>(
        (const bf16*)aggb, (const bf16*)W1T, t, nullptr, sums, N_NODES, HID, K1);
    k_bnrelu<<<(N_NODES*(HID/4)+255)/256, 256, 0, stream>>>(t, sums, bn1g + i*HID, bn1b + i*HID, tb, N_NODES, invM);

    const ushort_t* W2T = wb + 229376 + (size_t)i*65536;
    hipMemsetAsync(sums, 0, 2*HID*4, stream);
    k_mgemm<128, 128, 0><<<dim3(2, MPAD/128), 256, 0, stream>>>(
        (const bf16*)tb, (const bf16*)W2T, t, nullptr, sums, N_NODES, HID, HID);
    k_bnrelu<<<(N_NODES*(HID/4)+255)/256, 256, 0, stream>>>(t, sums, bn2g + i*HID, bn2b + i*HID, xb, N_NODES, invM);

    const ushort_t* pWT = wb + 499712 + (size_t)i*16384;
    k_mgemm<128, 64, 2><<<dim3(1, MPAD/128), 128, 0, stream>>>(
        (const bf16*)xb, (const bf16*)pWT, out, nullptr, nullptr, N_NODES, OUT_DIM, HID);
  }
}

// Round 4
// 724.370 us; speedup vs baseline: 3.0744x; 1.0856x over previous
//
#include <hip/hip_runtime.h>

#define N_NODES 50000
#define MPAD    50176
#define N_EDGES 800000
#define IN_DIM 128
#define HID 256
#define OUT_DIM 64
#define N_CONV 4
#define KCAT 1152   // 128 + 4*256

typedef __bf16 bf16;
typedef __attribute__((ext_vector_type(8))) __bf16 bf16x8;
typedef __attribute__((ext_vector_type(4))) float f32x4;
typedef unsigned short ushort_t;

__device__ __forceinline__ unsigned short f2b(float f){
  unsigned u = __float_as_uint(f);
  u += 0x7fffu + ((u >> 16) & 1u);
  return (unsigned short)(u >> 16);
}
__device__ __forceinline__ float b2f_lo(unsigned v){ return __uint_as_float(v << 16); }
__device__ __forceinline__ float b2f_hi(unsigned v){ return __uint_as_float(v & 0xffff0000u); }

__device__ __forceinline__ void stage16(const void* g, void* l){
  __builtin_amdgcn_global_load_lds((const __attribute__((address_space(1))) unsigned int*)g,
                                   (__attribute__((address_space(3))) unsigned int*)l, 16, 0, 0);
}

// ---------------- CSR build ----------------
__global__ void k_count(const int* __restrict__ dst, int* __restrict__ cnt, int ne){
  int e = blockIdx.x*blockDim.x + threadIdx.x;
  if (e < ne) atomicAdd(&cnt[dst[e]], 1);
}

__global__ void k_scan1(const int* __restrict__ cnt, int* __restrict__ scanned,
                        int* __restrict__ bsum, int n){
  int i = blockIdx.x*256 + threadIdx.x;
  int v = (i < n) ? cnt[i] : 0;
  int lane = threadIdx.x & 63;
  #pragma unroll
  for (int off = 1; off < 64; off <<= 1){
    int t = __shfl_up(v, off, 64);
    if (lane >= off) v += t;
  }
  __shared__ int wsum[4];
  int wv = threadIdx.x >> 6;
  if (lane == 63) wsum[wv] = v;
  __syncthreads();
  if (threadIdx.x == 0){
    int s = 0;
    #pragma unroll
    for (int k = 0; k < 4; ++k){ int t = wsum[k]; wsum[k] = s; s += t; }
    bsum[blockIdx.x] = s;
  }
  __syncthreads();
  v += wsum[wv];
  if (i < n) scanned[i] = v;
}

__global__ void k_scan2(int* __restrict__ bsum, int nb){
  __shared__ int sd[256];
  int i = threadIdx.x;
  sd[i] = (i < nb) ? bsum[i] : 0;
  __syncthreads();
  #pragma unroll
  for (int off = 1; off < 256; off <<= 1){
    int t = (i >= off) ? sd[i-off] : 0;
    __syncthreads();
    sd[i] += t;
    __syncthreads();
  }
  if (i < nb) bsum[i] = sd[i];
}

__global__ void k_scan3(const int* __restrict__ scanned, const int* __restrict__ bsum,
                        const int* __restrict__ cnt, int* __restrict__ row_ptr,
                        int* __restrict__ cursor, int n){
  int i = blockIdx.x*256 + threadIdx.x;
  if (i < n){
    int off = (blockIdx.x > 0) ? bsum[blockIdx.x-1] : 0;
    int inc = scanned[i] + off;
    row_ptr[i+1] = inc;
    cursor[i] = inc - cnt[i];
  }
  if (i == 0) row_ptr[0] = 0;
}

__global__ void k_fill(const int* __restrict__ src, const int* __restrict__ dst,
                       int* __restrict__ cursor, int* __restrict__ esrc, int ne){
  int e = blockIdx.x*blockDim.x + threadIdx.x;
  if (e < ne){
    int p = atomicAdd(&cursor[dst[e]], 1);
    esrc[p] = src[e];
  }
}

// ---------------- aggregation from xcat slice (bf16, fp32 accum, 8x MLP) ----------------
// x points at column start inside xcat; row stride KCAT elements. Output contiguous [n][D].
template<int D>
__global__ void k_agg(const ushort_t* __restrict__ x, const int* __restrict__ rp,
                      const int* __restrict__ es, ushort_t* __restrict__ agg, int n){
  int gw = (int)((blockIdx.x*(size_t)blockDim.x + threadIdx.x) >> 6);
  int lane = threadIdx.x & 63;
  if (gw >= n) return;
  if (D == 256){
    const uint2* xp = (const uint2*)x; const int S = KCAT/4;
    uint2 v = xp[(size_t)gw*S + lane];
    float a0=b2f_lo(v.x), a1=b2f_hi(v.x), a2=b2f_lo(v.y), a3=b2f_hi(v.y);
    float c0=0.f, c1=0.f, c2=0.f, c3=0.f;
    int e = rp[gw], e1 = rp[gw+1];
    for (; e + 8 <= e1; e += 8){
      int s[8];
      #pragma unroll
      for (int u = 0; u < 8; ++u) s[u] = __builtin_amdgcn_readfirstlane(es[e+u]);
      uint2 w[8];
      #pragma unroll
      for (int u = 0; u < 8; ++u) w[u] = xp[(size_t)s[u]*S + lane];
      #pragma unroll
      for (int u = 0; u < 8; u += 2){
        a0 += b2f_lo(w[u].x);   a1 += b2f_hi(w[u].x);   a2 += b2f_lo(w[u].y);   a3 += b2f_hi(w[u].y);
        c0 += b2f_lo(w[u+1].x); c1 += b2f_hi(w[u+1].x); c2 += b2f_lo(w[u+1].y); c3 += b2f_hi(w[u+1].y);
      }
    }
    for (; e + 2 <= e1; e += 2){
      int s0 = __builtin_amdgcn_readfirstlane(es[e]);
      int s1i = __builtin_amdgcn_readfirstlane(es[e+1]);
      uint2 w0 = xp[(size_t)s0*S + lane];
      uint2 w1 = xp[(size_t)s1i*S + lane];
      a0 += b2f_lo(w0.x); a1 += b2f_hi(w0.x); a2 += b2f_lo(w0.y); a3 += b2f_hi(w0.y);
      c0 += b2f_lo(w1.x); c1 += b2f_hi(w1.x); c2 += b2f_lo(w1.y); c3 += b2f_hi(w1.y);
    }
    if (e < e1){
      int s0 = __builtin_amdgcn_readfirstlane(es[e]);
      uint2 w0 = xp[(size_t)s0*S + lane];
      a0 += b2f_lo(w0.x); a1 += b2f_hi(w0.x); a2 += b2f_lo(w0.y); a3 += b2f_hi(w0.y);
    }
    a0 += c0; a1 += c1; a2 += c2; a3 += c3;
    unsigned o0 = (unsigned)f2b(a0) | ((unsigned)f2b(a1) << 16);
    unsigned o1 = (unsigned)f2b(a2) | ((unsigned)f2b(a3) << 16);
    *(uint2*)(agg + (size_t)gw*256 + lane*4) = make_uint2(o0, o1);
  } else {
    const unsigned* xp = (const unsigned*)x; const int S = KCAT/2;
    unsigned v = xp[(size_t)gw*S + lane];
    float a0 = b2f_lo(v), a1 = b2f_hi(v);
    float c0 = 0.f, c1 = 0.f;
    int e = rp[gw], e1 = rp[gw+1];
    for (; e + 8 <= e1; e += 8){
      int s[8];
      #pragma unroll
      for (int u = 0; u < 8; ++u) s[u] = __builtin_amdgcn_readfirstlane(es[e+u]);
      unsigned w[8];
      #pragma unroll
      for (int u = 0; u < 8; ++u) w[u] = xp[(size_t)s[u]*S + lane];
      #pragma unroll
      for (int u = 0; u < 8; u += 2){
        a0 += b2f_lo(w[u]);   a1 += b2f_hi(w[u]);
        c0 += b2f_lo(w[u+1]); c1 += b2f_hi(w[u+1]);
      }
    }
    for (; e + 2 <= e1; e += 2){
      int s0 = __builtin_amdgcn_readfirstlane(es[e]);
      int s1i = __builtin_amdgcn_readfirstlane(es[e+1]);
      unsigned w0 = xp[(size_t)s0*S + lane];
      unsigned w1 = xp[(size_t)s1i*S + lane];
      a0 += b2f_lo(w0); a1 += b2f_hi(w0);
      c0 += b2f_lo(w1); c1 += b2f_hi(w1);
    }
    if (e < e1){
      int s0 = __builtin_amdgcn_readfirstlane(es[e]);
      unsigned w0 = xp[(size_t)s0*S + lane];
      a0 += b2f_lo(w0); a1 += b2f_hi(w0);
    }
    a0 += c0; a1 += c1;
    unsigned o = (unsigned)f2b(a0) | ((unsigned)f2b(a1) << 16);
    *(unsigned*)(agg + (size_t)gw*128 + lane*2) = o;
  }
}

// ---------------- BN+ReLU (bf16 in, bf16 out, inline stats, strided output) ----------------
__global__ void k_bnrelu(const ushort_t* __restrict__ t, const float* __restrict__ sums,
                         const float* __restrict__ g, const float* __restrict__ b,
                         ushort_t* __restrict__ o, int ostride, int M, float invM){
  int idx = blockIdx.x*blockDim.x + threadIdx.x;
  if (idx >= M*(HID/8)) return;
  int row = idx >> 5, cg = (idx & 31) * 8;
  uint4 v = *(const uint4*)(t + (size_t)row*HID + cg);
  unsigned wv[4] = {v.x, v.y, v.z, v.w};
  unsigned ov[4];
  #pragma unroll
  for (int p = 0; p < 4; ++p){
    int c0 = cg + 2*p, c1 = c0 + 1;
    float m0 = sums[c0]*invM, m1 = sums[c1]*invM;
    float r0 = rsqrtf(sums[HID+c0]*invM - m0*m0 + 1e-5f);
    float r1 = rsqrtf(sums[HID+c1]*invM - m1*m1 + 1e-5f);
    float y0 = (b2f_lo(wv[p]) - m0)*r0*g[c0] + b[c0];
    float y1 = (b2f_hi(wv[p]) - m1)*r1*g[c1] + b[c1];
    y0 = y0 > 0.f ? y0 : 0.f; y1 = y1 > 0.f ? y1 : 0.f;
    ov[p] = (unsigned)f2b(y0) | ((unsigned)f2b(y1) << 16);
  }
  *(uint4*)(o + (size_t)row*ostride + cg) = make_uint4(ov[0], ov[1], ov[2], ov[3]);
}

// ---------------- h fp32 -> bf16 into xcat col 0..127 ----------------
__global__ void k_f2b(const float* __restrict__ in, ushort_t* __restrict__ xcat, int n8){
  int idx = blockIdx.x*blockDim.x + threadIdx.x;
  if (idx >= n8) return;
  int row = idx >> 4, cg = (idx & 15) * 8;
  float4 a = *(const float4*)(in + (size_t)row*IN_DIM + cg);
  float4 c = *(const float4*)(in + (size_t)row*IN_DIM + cg + 4);
  unsigned o0 = (unsigned)f2b(a.x) | ((unsigned)f2b(a.y) << 16);
  unsigned o1 = (unsigned)f2b(a.z) | ((unsigned)f2b(a.w) << 16);
  unsigned o2 = (unsigned)f2b(c.x) | ((unsigned)f2b(c.y) << 16);
  unsigned o3 = (unsigned)f2b(c.z) | ((unsigned)f2b(c.w) << 16);
  *(uint4*)(xcat + (size_t)row*KCAT + cg) = make_uint4(o0, o1, o2, o3);
}

// ---------------- weight transpose + convert ----------------
__global__ void k_wprep(const float* __restrict__ c0W1, const float* __restrict__ cW1,
                        const float* __restrict__ cW2, const float* __restrict__ p0W,
                        const float* __restrict__ pW,
                        ushort_t* __restrict__ wb, ushort_t* __restrict__ whead){
  int m = blockIdx.y;
  const float* src; int R, C; ushort_t* dst; int dstride, dcol;
  if (m == 0){       src = c0W1;              R = 128; C = 256; dst = wb;                       dstride = 128;  dcol = 0; }
  else if (m <= 3){  src = cW1 + (m-1)*65536; R = 256; C = 256; dst = wb + 32768 + (m-1)*65536; dstride = 256;  dcol = 0; }
  else if (m <= 7){  src = cW2 + (m-4)*65536; R = 256; C = 256; dst = wb + 229376 + (m-4)*65536;dstride = 256;  dcol = 0; }
  else if (m == 8){  src = p0W;               R = 128; C = 64;  dst = whead;                    dstride = KCAT; dcol = 0; }
  else {             src = pW + (m-9)*16384;  R = 256; C = 64;  dst = whead;                    dstride = KCAT; dcol = 128 + (m-9)*256; }
  int tx = R/64, tiles = tx * (C/64);
  int t = blockIdx.x;
  if (t >= tiles) return;
  int sr0 = (t % tx)*64, sc0 = (t / tx)*64;
  __shared__ float ld[64][65];
  int c = threadIdx.x & 63, rq = threadIdx.x >> 6;
  #pragma unroll
  for (int i = 0; i < 16; ++i){
    int rr = i*4 + rq;
    ld[rr][c] = src[(size_t)(sr0+rr)*C + sc0 + c];
  }
  __syncthreads();
  #pragma unroll
  for (int i = 0; i < 16; ++i){
    int rr = i*4 + rq;
    dst[(size_t)(sc0+rr)*dstride + dcol + sr0 + c] = f2b(ld[c][rr]);
  }
}

__global__ void k_biasall(const float* __restrict__ p0b, const float* __restrict__ pb,
                          float* __restrict__ ball){
  int c = threadIdx.x;
  float v = p0b[c];
  #pragma unroll
  for (int i = 0; i < N_CONV; ++i) v += pb[i*OUT_DIM + c];
  ball[c] = v;
}

// ---------------- MFMA GEMM: C[M,N] = A[M,K](bf16) @ BT[N,K](bf16)^T ----------------
// MODE 0: round acc->bf16, stats from rounded values, write bf16 C (all rows incl pad)
// MODE 1: write fp32 C + bias[col], masked row<M
template<int BM, int BN, int MODE>
__global__ __launch_bounds__((BM/64)*(BN/64)*64)
void k_mgemm(const bf16* __restrict__ A, const bf16* __restrict__ BT,
             void* __restrict__ Cv, const float* __restrict__ bias,
             float* __restrict__ sums, int M, int N, int K)
{
  constexpr int NW  = (BM/64)*(BN/64);
  constexpr int WNT = BN/64;
  constexpr int ACH = BM/16, BCH = BN/16;
  __shared__ __align__(16) bf16 As[2*BM*32];
  __shared__ __align__(16) bf16 Bs[2*BN*32];
  const int tid = threadIdx.x;
  const int wid = tid >> 6, l = tid & 63;
  const int wm = wid / WNT, wn = wid % WNT;
  const int m0 = blockIdx.y * BM, n0 = blockIdx.x * BN;
  const int r = l & 15, q = l >> 4;
  const int fragByte = ((q ^ ((r >> 1) & 3)) << 4);
  const int wrow = l >> 2;
  const int wk = (((l & 3) ^ ((l >> 3) & 3)) << 3);

  auto STAGE = [&](int buf, int k0){
    #pragma unroll
    for (int c = 0; c < ACH/NW; ++c){
      int ch = wid + c*NW;
      const bf16* g = A + (size_t)(m0 + ch*16 + wrow)*K + (k0 + wk);
      stage16(g, (char*)As + buf*(BM*64) + ch*1024);
    }
    #pragma unroll
    for (int c = 0; c < BCH/NW; ++c){
      int ch = wid + c*NW;
      const bf16* g = BT + (size_t)(n0 + ch*16 + wrow)*K + (k0 + wk);
      stage16(g, (char*)Bs + buf*(BN*64) + ch*1024);
    }
  };

  f32x4 acc[4][4] = {};
  const int nt = K >> 5;
  STAGE(0, 0);
  for (int t = 0; t < nt; ++t){
    int cur = t & 1;
    __syncthreads();
    if (t + 1 < nt) STAGE(cur ^ 1, (t + 1) << 5);
    bf16x8 af[4], bfr[4];
    #pragma unroll
    for (int mf = 0; mf < 4; ++mf)
      af[mf] = *(const bf16x8*)((const char*)As + cur*(BM*64) + (wm*64 + mf*16 + r)*64 + fragByte);
    #pragma unroll
    for (int nf = 0; nf < 4; ++nf)
      bfr[nf] = *(const bf16x8*)((const char*)Bs + cur*(BN*64) + (wn*64 + nf*16 + r)*64 + fragByte);
    #pragma unroll
    for (int mf = 0; mf < 4; ++mf)
      #pragma unroll
      for (int nf = 0; nf < 4; ++nf)
        acc[mf][nf] = __builtin_amdgcn_mfma_f32_16x16x32_bf16(af[mf], bfr[nf], acc[mf][nf], 0, 0, 0);
  }

  if (MODE == 0){
    ushort_t* Cb = (ushort_t*)Cv;
    float s1[4] = {0.f,0.f,0.f,0.f}, s2[4] = {0.f,0.f,0.f,0.f};
    #pragma unroll
    for (int mf = 0; mf < 4; ++mf){
      #pragma unroll
      for (int j = 0; j < 4; ++j){
        int row = m0 + wm*64 + mf*16 + q*4 + j;
        #pragma unroll
        for (int nf = 0; nf < 4; ++nf){
          unsigned short us = f2b(acc[mf][nf][j]);
          float vr = __uint_as_float((unsigned)us << 16);
          s1[nf] += vr; s2[nf] = fmaf(vr, vr, s2[nf]);
          Cb[(size_t)row*N + n0 + wn*64 + nf*16 + r] = us;
        }
      }
    }
    #pragma unroll
    for (int nf = 0; nf < 4; ++nf){
      float a = s1[nf], c = s2[nf];
      a += __shfl_xor(a, 16, 64); a += __shfl_xor(a, 32, 64);
      c += __shfl_xor(c, 16, 64); c += __shfl_xor(c, 32, 64);
      if (q == 0){
        int col = n0 + wn*64 + nf*16 + r;
        atomicAdd(&sums[col], a);
        atomicAdd(&sums[256 + col], c);
      }
    }
  } else {
    float* C = (float*)Cv;
    #pragma unroll
    for (int mf = 0; mf < 4; ++mf){
      #pragma unroll
      for (int j = 0; j < 4; ++j){
        int row = m0 + wm*64 + mf*16 + q*4 + j;
        if (row >= M) continue;
        #pragma unroll
        for (int nf = 0; nf < 4; ++nf){
          int col = n0 + wn*64 + nf*16 + r;
          C[(size_t)row*N + col] = acc[mf][nf][j] + bias[col];
        }
      }
    }
  }
}

extern "C" void kernel_launch(void* const* d_in, const int* in_sizes, int n_in,
                              void* d_out, int out_size, void* d_ws, size_t ws_size,
                              hipStream_t stream){
  const float* h    = (const float*)d_in[0];
  const float* c0W1 = (const float*)d_in[1];
  const float* cW1  = (const float*)d_in[2];
  const float* cW2  = (const float*)d_in[3];
  const float* bn1g = (const float*)d_in[4];
  const float* bn1b = (const float*)d_in[5];
  const float* bn2g = (const float*)d_in[6];
  const float* bn2b = (const float*)d_in[7];
  const float* p0W  = (const float*)d_in[8];
  const float* p0b  = (const float*)d_in[9];
  const float* pW   = (const float*)d_in[10];
  const float* pb   = (const float*)d_in[11];
  const int* src    = (const int*)d_in[12];
  const int* dst    = (const int*)d_in[13];
  float* out = (float*)d_out;

  char* w = (char*)d_ws;
  auto alloc = [&](size_t bytes)->char*{ char* p = w; w += (bytes + 255) & ~(size_t)255; return p; };
  ushort_t* xcat = (ushort_t*)alloc((size_t)MPAD*KCAT*2);   // 115.6 MB
  ushort_t* aggb = (ushort_t*)alloc((size_t)MPAD*HID*2);    // 25.7 MB
  ushort_t* tt   = (ushort_t*)alloc((size_t)MPAD*HID*2);    // 25.7 MB
  ushort_t* wb   = (ushort_t*)alloc((size_t)491520*2);
  ushort_t* whead= (ushort_t*)alloc((size_t)OUT_DIM*KCAT*2);
  int* row_ptr   = (int*)alloc((N_NODES+1)*4);
  int* cursor    = (int*)alloc(N_NODES*4);
  int* counts    = (int*)alloc(N_NODES*4);
  int* esrc      = (int*)alloc(N_EDGES*4);
  int* scanned   = (int*)alloc(N_NODES*4);
  int* bsum      = (int*)alloc(256*4);
  float* sums    = (float*)alloc(2*HID*4);
  float* ball    = (float*)alloc(OUT_DIM*4);

  // aggb pad rows must be zero for layer-0 GEMM1 stats (128-wide view).
  // 256-view pads are written =0 by every MODE-0 GEMM2 (A pads are 0), self-sustaining.
  hipMemsetAsync(aggb + (size_t)N_NODES*IN_DIM, 0, (size_t)(MPAD-N_NODES)*IN_DIM*2, stream);
  hipMemsetAsync(aggb + (size_t)N_NODES*HID,    0, (size_t)(MPAD-N_NODES)*HID*2,    stream);

  // ---- CSR build (by dst) ----
  const int NB = (N_NODES + 255) / 256;
  hipMemsetAsync(counts, 0, N_NODES*4, stream);
  k_count<<<(N_EDGES+255)/256, 256, 0, stream>>>(dst, counts, N_EDGES);
  k_scan1<<<NB, 256, 0, stream>>>(counts, scanned, bsum, N_NODES);
  k_scan2<<<1, 256, 0, stream>>>(bsum, NB);
  k_scan3<<<NB, 256, 0, stream>>>(scanned, bsum, counts, row_ptr, cursor, N_NODES);
  k_fill<<<(N_EDGES+255)/256, 256, 0, stream>>>(src, dst, cursor, esrc, N_EDGES);

  // ---- weight prep + h->xcat + fused bias ----
  k_wprep<<<dim3(16, 13), 256, 0, stream>>>(c0W1, cW1, cW2, p0W, pW, wb, whead);
  k_f2b<<<(N_NODES*16 + 255)/256, 256, 0, stream>>>(h, xcat, N_NODES*16);
  k_biasall<<<1, OUT_DIM, 0, stream>>>(p0b, pb, ball);

  const float invM = 1.0f / (float)N_NODES;
  for (int i = 0; i < N_CONV; ++i){
    int K1 = (i == 0) ? IN_DIM : HID;
    const ushort_t* xin = (i == 0) ? xcat : (xcat + 128 + (size_t)(i-1)*HID);
    if (i == 0)
      k_agg<IN_DIM><<<(N_NODES*64+255)/256, 256, 0, stream>>>(xin, row_ptr, esrc, aggb, N_NODES);
    else
      k_agg<HID><<<(N_NODES*64+255)/256, 256, 0, stream>>>(xin, row_ptr, esrc, aggb, N_NODES);

    const ushort_t* W1T = (i == 0) ? wb : (wb + 32768 + (size_t)(i-1)*65536);
    hipMemsetAsync(sums, 0, 2*HID*4, stream);
    k_mgemm<128, 128, 0><<<dim3(2, MPAD/128), 256, 0, stream>>>(
        (const bf16*)aggb, (const bf16*)W1T, tt, nullptr, sums, N_NODES, HID, K1);
    k_bnrelu<<<(N_NODES*32 + 255)/256, 256, 0, stream>>>(
        tt, sums, bn1g + i*HID, bn1b + i*HID, tt, HID, N_NODES, invM);

    const ushort_t* W2T = wb + 229376 + (size_t)i*65536;
    hipMemsetAsync(sums, 0, 2*HID*4, stream);
    k_mgemm<128, 128, 0><<<dim3(2, MPAD/128), 256, 0, stream>>>(
        (const bf16*)tt, (const bf16*)W2T, aggb, nullptr, sums, N_NODES, HID, HID);
    k_bnrelu<<<(N_NODES*32 + 255)/256, 256, 0, stream>>>(
        aggb, sums, bn2g + i*HID, bn2b + i*HID, xcat + 128 + (size_t)i*HID, KCAT, N_NODES, invM);
  }

  // ---- one consolidated jumping-knowledge head GEMM: out = xcat @ whead^T + ball ----
  k_mgemm<128, 64, 1><<<dim3(1, MPAD/128), 128, 0, stream>>>(
      (const bf16*)xcat, (const bf16*)whead, out, ball, nullptr, N_NODES, OUT_DIM, KCAT);
}

// Round 5
// 679.214 us; speedup vs baseline: 3.2788x; 1.0665x over previous
//
#include <hip/hip_runtime.h>

#define N_NODES 50000
#define MPAD    50176
#define N_EDGES 800000
#define IN_DIM 128
#define HID 256
#define OUT_DIM 64
#define N_CONV 4
#define KCAT 1152   // 128 + 4*256

typedef __bf16 bf16;
typedef __attribute__((ext_vector_type(8))) __bf16 bf16x8;
typedef __attribute__((ext_vector_type(4))) float f32x4;
typedef unsigned short ushort_t;

__device__ __forceinline__ unsigned short f2b(float f){
  unsigned u = __float_as_uint(f);
  u += 0x7fffu + ((u >> 16) & 1u);
  return (unsigned short)(u >> 16);
}
__device__ __forceinline__ float b2f_lo(unsigned v){ return __uint_as_float(v << 16); }
__device__ __forceinline__ float b2f_hi(unsigned v){ return __uint_as_float(v & 0xffff0000u); }

__device__ __forceinline__ void stage16(const void* g, void* l){
  __builtin_amdgcn_global_load_lds((const __attribute__((address_space(1))) unsigned int*)g,
                                   (__attribute__((address_space(3))) unsigned int*)l, 16, 0, 0);
}

// ---------------- CSR build ----------------
__global__ void k_count(const int* __restrict__ dst, int* __restrict__ cnt, int ne){
  int e = blockIdx.x*blockDim.x + threadIdx.x;
  if (e < ne) atomicAdd(&cnt[dst[e]], 1);
}

__global__ void k_scan1(const int* __restrict__ cnt, int* __restrict__ scanned,
                        int* __restrict__ bsum, int n){
  int i = blockIdx.x*256 + threadIdx.x;
  int v = (i < n) ? cnt[i] : 0;
  int lane = threadIdx.x & 63;
  #pragma unroll
  for (int off = 1; off < 64; off <<= 1){
    int t = __shfl_up(v, off, 64);
    if (lane >= off) v += t;
  }
  __shared__ int wsum[4];
  int wv = threadIdx.x >> 6;
  if (lane == 63) wsum[wv] = v;
  __syncthreads();
  if (threadIdx.x == 0){
    int s = 0;
    #pragma unroll
    for (int k = 0; k < 4; ++k){ int t = wsum[k]; wsum[k] = s; s += t; }
    bsum[blockIdx.x] = s;
  }
  __syncthreads();
  v += wsum[wv];
  if (i < n) scanned[i] = v;
}

__global__ void k_scan2(int* __restrict__ bsum, int nb){
  __shared__ int sd[256];
  int i = threadIdx.x;
  sd[i] = (i < nb) ? bsum[i] : 0;
  __syncthreads();
  #pragma unroll
  for (int off = 1; off < 256; off <<= 1){
    int t = (i >= off) ? sd[i-off] : 0;
    __syncthreads();
    sd[i] += t;
    __syncthreads();
  }
  if (i < nb) bsum[i] = sd[i];
}

__global__ void k_scan3(const int* __restrict__ scanned, const int* __restrict__ bsum,
                        const int* __restrict__ cnt, int* __restrict__ row_ptr,
                        int* __restrict__ cursor, int n){
  int i = blockIdx.x*256 + threadIdx.x;
  if (i < n){
    int off = (blockIdx.x > 0) ? bsum[blockIdx.x-1] : 0;
    int inc = scanned[i] + off;
    row_ptr[i+1] = inc;
    cursor[i] = inc - cnt[i];
  }
  if (i == 0) row_ptr[0] = 0;
}

__global__ void k_fill(const int* __restrict__ src, const int* __restrict__ dst,
                       int* __restrict__ cursor, int* __restrict__ esrc, int ne){
  int e = blockIdx.x*blockDim.x + threadIdx.x;
  if (e < ne){
    int p = atomicAdd(&cursor[dst[e]], 1);
    esrc[p] = src[e];
  }
}

// ---------------- aggregation from xcat slice (bf16, fp32 accum, 8x MLP) ----------------
template<int D>
__global__ void k_agg(const ushort_t* __restrict__ x, const int* __restrict__ rp,
                      const int* __restrict__ es, ushort_t* __restrict__ agg, int n){
  int gw = (int)((blockIdx.x*(size_t)blockDim.x + threadIdx.x) >> 6);
  int lane = threadIdx.x & 63;
  if (gw >= n) return;
  if (D == 256){
    const uint2* xp = (const uint2*)x; const int S = KCAT/4;
    uint2 v = xp[(size_t)gw*S + lane];
    float a0=b2f_lo(v.x), a1=b2f_hi(v.x), a2=b2f_lo(v.y), a3=b2f_hi(v.y);
    float c0=0.f, c1=0.f, c2=0.f, c3=0.f;
    int e = rp[gw], e1 = rp[gw+1];
    for (; e + 8 <= e1; e += 8){
      uint2 w[8];
      #pragma unroll
      for (int u = 0; u < 8; ++u) w[u] = xp[(size_t)es[e+u]*S + lane];
      #pragma unroll
      for (int u = 0; u < 8; u += 2){
        a0 += b2f_lo(w[u].x);   a1 += b2f_hi(w[u].x);   a2 += b2f_lo(w[u].y);   a3 += b2f_hi(w[u].y);
        c0 += b2f_lo(w[u+1].x); c1 += b2f_hi(w[u+1].x); c2 += b2f_lo(w[u+1].y); c3 += b2f_hi(w[u+1].y);
      }
    }
    for (; e + 2 <= e1; e += 2){
      uint2 w0 = xp[(size_t)es[e]*S + lane];
      uint2 w1 = xp[(size_t)es[e+1]*S + lane];
      a0 += b2f_lo(w0.x); a1 += b2f_hi(w0.x); a2 += b2f_lo(w0.y); a3 += b2f_hi(w0.y);
      c0 += b2f_lo(w1.x); c1 += b2f_hi(w1.x); c2 += b2f_lo(w1.y); c3 += b2f_hi(w1.y);
    }
    if (e < e1){
      uint2 w0 = xp[(size_t)es[e]*S + lane];
      a0 += b2f_lo(w0.x); a1 += b2f_hi(w0.x); a2 += b2f_lo(w0.y); a3 += b2f_hi(w0.y);
    }
    a0 += c0; a1 += c1; a2 += c2; a3 += c3;
    unsigned o0 = (unsigned)f2b(a0) | ((unsigned)f2b(a1) << 16);
    unsigned o1 = (unsigned)f2b(a2) | ((unsigned)f2b(a3) << 16);
    *(uint2*)(agg + (size_t)gw*256 + lane*4) = make_uint2(o0, o1);
  } else {
    const unsigned* xp = (const unsigned*)x; const int S = KCAT/2;
    unsigned v = xp[(size_t)gw*S + lane];
    float a0 = b2f_lo(v), a1 = b2f_hi(v);
    float c0 = 0.f, c1 = 0.f;
    int e = rp[gw], e1 = rp[gw+1];
    for (; e + 8 <= e1; e += 8){
      unsigned w[8];
      #pragma unroll
      for (int u = 0; u < 8; ++u) w[u] = xp[(size_t)es[e+u]*S + lane];
      #pragma unroll
      for (int u = 0; u < 8; u += 2){
        a0 += b2f_lo(w[u]);   a1 += b2f_hi(w[u]);
        c0 += b2f_lo(w[u+1]); c1 += b2f_hi(w[u+1]);
      }
    }
    for (; e + 2 <= e1; e += 2){
      unsigned w0 = xp[(size_t)es[e]*S + lane];
      unsigned w1 = xp[(size_t)es[e+1]*S + lane];
      a0 += b2f_lo(w0); a1 += b2f_hi(w0);
      c0 += b2f_lo(w1); c1 += b2f_hi(w1);
    }
    if (e < e1){
      unsigned w0 = xp[(size_t)es[e]*S + lane];
      a0 += b2f_lo(w0); a1 += b2f_hi(w0);
    }
    a0 += c0; a1 += c1;
    unsigned o = (unsigned)f2b(a0) | ((unsigned)f2b(a1) << 16);
    *(unsigned*)(agg + (size_t)gw*128 + lane*2) = o;
  }
}

// ---------------- BN+ReLU (bf16 in, bf16 out, inline stats, strided output) ----------------
__global__ void k_bnrelu(const ushort_t* __restrict__ t, const float* __restrict__ sums,
                         const float* __restrict__ g, const float* __restrict__ b,
                         ushort_t* __restrict__ o, int ostride, int M, float invM){
  int idx = blockIdx.x*blockDim.x + threadIdx.x;
  if (idx >= M*(HID/8)) return;
  int row = idx >> 5, cg = (idx & 31) * 8;
  uint4 v = *(const uint4*)(t + (size_t)row*HID + cg);
  unsigned wv[4] = {v.x, v.y, v.z, v.w};
  unsigned ov[4];
  #pragma unroll
  for (int p = 0; p < 4; ++p){
    int c0 = cg + 2*p, c1 = c0 + 1;
    float m0 = sums[c0]*invM, m1 = sums[c1]*invM;
    float r0 = rsqrtf(sums[HID+c0]*invM - m0*m0 + 1e-5f);
    float r1 = rsqrtf(sums[HID+c1]*invM - m1*m1 + 1e-5f);
    float y0 = (b2f_lo(wv[p]) - m0)*r0*g[c0] + b[c0];
    float y1 = (b2f_hi(wv[p]) - m1)*r1*g[c1] + b[c1];
    y0 = y0 > 0.f ? y0 : 0.f; y1 = y1 > 0.f ? y1 : 0.f;
    ov[p] = (unsigned)f2b(y0) | ((unsigned)f2b(y1) << 16);
  }
  *(uint4*)(o + (size_t)row*ostride + cg) = make_uint4(ov[0], ov[1], ov[2], ov[3]);
}

// ---------------- h fp32 -> bf16 into xcat col 0..127 ----------------
__global__ void k_f2b(const float* __restrict__ in, ushort_t* __restrict__ xcat, int n8){
  int idx = blockIdx.x*blockDim.x + threadIdx.x;
  if (idx >= n8) return;
  int row = idx >> 4, cg = (idx & 15) * 8;
  float4 a = *(const float4*)(in + (size_t)row*IN_DIM + cg);
  float4 c = *(const float4*)(in + (size_t)row*IN_DIM + cg + 4);
  unsigned o0 = (unsigned)f2b(a.x) | ((unsigned)f2b(a.y) << 16);
  unsigned o1 = (unsigned)f2b(a.z) | ((unsigned)f2b(a.w) << 16);
  unsigned o2 = (unsigned)f2b(c.x) | ((unsigned)f2b(c.y) << 16);
  unsigned o3 = (unsigned)f2b(c.z) | ((unsigned)f2b(c.w) << 16);
  *(uint4*)(xcat + (size_t)row*KCAT + cg) = make_uint4(o0, o1, o2, o3);
}

// ---------------- weight transpose + convert (+ fused bias fold) ----------------
__global__ void k_wprep(const float* __restrict__ c0W1, const float* __restrict__ cW1,
                        const float* __restrict__ cW2, const float* __restrict__ p0W,
                        const float* __restrict__ pW,
                        const float* __restrict__ p0b, const float* __restrict__ pb,
                        ushort_t* __restrict__ wb, ushort_t* __restrict__ whead,
                        float* __restrict__ ball){
  int m = blockIdx.y;
  if (m == 13){
    if (blockIdx.x == 0 && threadIdx.x < OUT_DIM){
      int c = threadIdx.x;
      float v = p0b[c];
      #pragma unroll
      for (int i = 0; i < N_CONV; ++i) v += pb[i*OUT_DIM + c];
      ball[c] = v;
    }
    return;
  }
  const float* src; int R, C; ushort_t* dst; int dstride, dcol;
  if (m == 0){       src = c0W1;              R = 128; C = 256; dst = wb;                       dstride = 128;  dcol = 0; }
  else if (m <= 3){  src = cW1 + (m-1)*65536; R = 256; C = 256; dst = wb + 32768 + (m-1)*65536; dstride = 256;  dcol = 0; }
  else if (m <= 7){  src = cW2 + (m-4)*65536; R = 256; C = 256; dst = wb + 229376 + (m-4)*65536;dstride = 256;  dcol = 0; }
  else if (m == 8){  src = p0W;               R = 128; C = 64;  dst = whead;                    dstride = KCAT; dcol = 0; }
  else {             src = pW + (m-9)*16384;  R = 256; C = 64;  dst = whead;                    dstride = KCAT; dcol = 128 + (m-9)*256; }
  int tx = R/64, tiles = tx * (C/64);
  int t = blockIdx.x;
  if (t >= tiles) return;
  int sr0 = (t % tx)*64, sc0 = (t / tx)*64;
  __shared__ float ld[64][65];
  int c = threadIdx.x & 63, rq = threadIdx.x >> 6;
  #pragma unroll
  for (int i = 0; i < 16; ++i){
    int rr = i*4 + rq;
    ld[rr][c] = src[(size_t)(sr0+rr)*C + sc0 + c];
  }
  __syncthreads();
  #pragma unroll
  for (int i = 0; i < 16; ++i){
    int rr = i*4 + rq;
    dst[(size_t)(sc0+rr)*dstride + dcol + sr0 + c] = f2b(ld[c][rr]);
  }
}

// ---------------- MFMA GEMM: C[M,N] = A[M,K](bf16) @ BT[N,K](bf16)^T ----------------
// MODE 0: round acc->bf16, fused column stats from rounded values, bf16 C (all rows incl pad)
// MODE 1: fp32 C + bias[col], masked row<M
// MODE 2: like MODE 0, but A is reg-staged with fused BN(asums)+ReLU affine and pad-row zeroing
template<int BM, int BN, int MODE>
__global__ __launch_bounds__((BM/64)*(BN/64)*64)
void k_mgemm(const bf16* __restrict__ A, const bf16* __restrict__ BT,
             void* __restrict__ Cv, const float* __restrict__ bias,
             float* __restrict__ sums, const float* __restrict__ asums,
             const float* __restrict__ ag, const float* __restrict__ ab,
             int M, int N, int K, float invM)
{
  constexpr int NW  = (BM/64)*(BN/64);
  constexpr int WNT = BN/64;
  constexpr int ACH = BM/16, BCH = BN/16;
  __shared__ __align__(16) bf16 As[2*BM*32];
  __shared__ __align__(16) bf16 Bs[2*BN*32];
  __shared__ float sAf[MODE==2?256:1];
  __shared__ float tAf[MODE==2?256:1];
  const int tid = threadIdx.x;
  const int wid = tid >> 6, l = tid & 63;
  const int wm = wid / WNT, wn = wid % WNT;
  const int m0 = blockIdx.y * BM, n0 = blockIdx.x * BN;
  const int r = l & 15, q = l >> 4;
  const int fragByte = ((q ^ ((r >> 1) & 3)) << 4);
  const int wrow = l >> 2;
  const int wk = (((l & 3) ^ ((l >> 3) & 3)) << 3);

  if constexpr (MODE == 2){
    if (tid < 256){
      float m = asums[tid] * invM;
      float var = asums[256 + tid] * invM - m*m;
      float s = rsqrtf(var + 1e-5f) * ag[tid];
      sAf[tid] = s;
      tAf[tid] = ab[tid] - m*s;
    }
    __syncthreads();
  }

  auto STAGE = [&](int buf, int k0){
    #pragma unroll
    for (int c = 0; c < ACH/NW; ++c){
      int ch = wid + c*NW;
      if constexpr (MODE == 2){
        int grow = m0 + ch*16 + wrow;
        uint4 raw = *(const uint4*)(A + (size_t)grow*K + (k0 + wk));
        int kc = k0 + wk;
        unsigned rv[4] = {raw.x, raw.y, raw.z, raw.w};
        unsigned ov[4];
        #pragma unroll
        for (int p = 0; p < 4; ++p){
          int c0 = kc + 2*p, c1 = c0 + 1;
          float y0 = fmaf(b2f_lo(rv[p]), sAf[c0], tAf[c0]);
          float y1 = fmaf(b2f_hi(rv[p]), sAf[c1], tAf[c1]);
          y0 = y0 > 0.f ? y0 : 0.f; y1 = y1 > 0.f ? y1 : 0.f;
          ov[p] = (unsigned)f2b(y0) | ((unsigned)f2b(y1) << 16);
        }
        if (grow >= M){ ov[0]=0; ov[1]=0; ov[2]=0; ov[3]=0; }
        *(uint4*)((char*)As + buf*(BM*64) + ch*1024 + l*16) = make_uint4(ov[0],ov[1],ov[2],ov[3]);
      } else {
        const bf16* g = A + (size_t)(m0 + ch*16 + wrow)*K + (k0 + wk);
        stage16(g, (char*)As + buf*(BM*64) + ch*1024);
      }
    }
    #pragma unroll
    for (int c = 0; c < BCH/NW; ++c){
      int ch = wid + c*NW;
      const bf16* g = BT + (size_t)(n0 + ch*16 + wrow)*K + (k0 + wk);
      stage16(g, (char*)Bs + buf*(BN*64) + ch*1024);
    }
  };

  f32x4 acc[4][4] = {};
  const int nt = K >> 5;
  STAGE(0, 0);
  for (int t = 0; t < nt; ++t){
    int cur = t & 1;
    __syncthreads();
    if (t + 1 < nt) STAGE(cur ^ 1, (t + 1) << 5);
    bf16x8 af[4], bfr[4];
    #pragma unroll
    for (int mf = 0; mf < 4; ++mf)
      af[mf] = *(const bf16x8*)((const char*)As + cur*(BM*64) + (wm*64 + mf*16 + r)*64 + fragByte);
    #pragma unroll
    for (int nf = 0; nf < 4; ++nf)
      bfr[nf] = *(const bf16x8*)((const char*)Bs + cur*(BN*64) + (wn*64 + nf*16 + r)*64 + fragByte);
    #pragma unroll
    for (int mf = 0; mf < 4; ++mf)
      #pragma unroll
      for (int nf = 0; nf < 4; ++nf)
        acc[mf][nf] = __builtin_amdgcn_mfma_f32_16x16x32_bf16(af[mf], bfr[nf], acc[mf][nf], 0, 0, 0);
  }

  if (MODE == 0 || MODE == 2){
    ushort_t* Cb = (ushort_t*)Cv;
    float s1[4] = {0.f,0.f,0.f,0.f}, s2[4] = {0.f,0.f,0.f,0.f};
    #pragma unroll
    for (int mf = 0; mf < 4; ++mf){
      #pragma unroll
      for (int j = 0; j < 4; ++j){
        int row = m0 + wm*64 + mf*16 + q*4 + j;
        #pragma unroll
        for (int nf = 0; nf < 4; ++nf){
          unsigned short us = f2b(acc[mf][nf][j]);
          float vr = __uint_as_float((unsigned)us << 16);
          s1[nf] += vr; s2[nf] = fmaf(vr, vr, s2[nf]);
          Cb[(size_t)row*N + n0 + wn*64 + nf*16 + r] = us;
        }
      }
    }
    #pragma unroll
    for (int nf = 0; nf < 4; ++nf){
      float a = s1[nf], c = s2[nf];
      a += __shfl_xor(a, 16, 64); a += __shfl_xor(a, 32, 64);
      c += __shfl_xor(c, 16, 64); c += __shfl_xor(c, 32, 64);
      if (q == 0){
        int col = n0 + wn*64 + nf*16 + r;
        atomicAdd(&sums[col], a);
        atomicAdd(&sums[256 + col], c);
      }
    }
  } else {
    float* C = (float*)Cv;
    #pragma unroll
    for (int mf = 0; mf < 4; ++mf){
      #pragma unroll
      for (int j = 0; j < 4; ++j){
        int row = m0 + wm*64 + mf*16 + q*4 + j;
        if (row >= M) continue;
        #pragma unroll
        for (int nf = 0; nf < 4; ++nf){
          int col = n0 + wn*64 + nf*16 + r;
          C[(size_t)row*N + col] = acc[mf][nf][j] + bias[col];
        }
      }
    }
  }
}

extern "C" void kernel_launch(void* const* d_in, const int* in_sizes, int n_in,
                              void* d_out, int out_size, void* d_ws, size_t ws_size,
                              hipStream_t stream){
  const float* h    = (const float*)d_in[0];
  const float* c0W1 = (const float*)d_in[1];
  const float* cW1  = (const float*)d_in[2];
  const float* cW2  = (const float*)d_in[3];
  const float* bn1g = (const float*)d_in[4];
  const float* bn1b = (const float*)d_in[5];
  const float* bn2g = (const float*)d_in[6];
  const float* bn2b = (const float*)d_in[7];
  const float* p0W  = (const float*)d_in[8];
  const float* p0b  = (const float*)d_in[9];
  const float* pW   = (const float*)d_in[10];
  const float* pb   = (const float*)d_in[11];
  const int* src    = (const int*)d_in[12];
  const int* dst    = (const int*)d_in[13];
  float* out = (float*)d_out;

  char* w = (char*)d_ws;
  auto alloc = [&](size_t bytes)->char*{ char* p = w; w += (bytes + 255) & ~(size_t)255; return p; };
  ushort_t* xcat = (ushort_t*)alloc((size_t)MPAD*KCAT*2);
  ushort_t* aggb = (ushort_t*)alloc((size_t)MPAD*HID*2);
  ushort_t* tt   = (ushort_t*)alloc((size_t)MPAD*HID*2);
  ushort_t* wb   = (ushort_t*)alloc((size_t)491520*2);
  ushort_t* whead= (ushort_t*)alloc((size_t)OUT_DIM*KCAT*2);
  int* row_ptr   = (int*)alloc((N_NODES+1)*4);
  int* cursor    = (int*)alloc(N_NODES*4);
  int* counts    = (int*)alloc(N_NODES*4);
  int* esrc      = (int*)alloc(N_EDGES*4);
  int* scanned   = (int*)alloc(N_NODES*4);
  int* bsum      = (int*)alloc(256*4);
  float* sums8   = (float*)alloc(8*512*4);
  float* ball    = (float*)alloc(OUT_DIM*4);

  // pad-row zeroing (128-wide view for layer-0 GEMM1 + 256-wide view)
  hipMemsetAsync(aggb + (size_t)N_NODES*IN_DIM, 0, (size_t)(MPAD-N_NODES)*IN_DIM*2, stream);
  hipMemsetAsync(aggb + (size_t)N_NODES*HID,    0, (size_t)(MPAD-N_NODES)*HID*2,    stream);
  hipMemsetAsync(sums8, 0, 8*512*4, stream);

  // ---- CSR build (by dst) ----
  const int NB = (N_NODES + 255) / 256;
  hipMemsetAsync(counts, 0, N_NODES*4, stream);
  k_count<<<(N_EDGES+255)/256, 256, 0, stream>>>(dst, counts, N_EDGES);
  k_scan1<<<NB, 256, 0, stream>>>(counts, scanned, bsum, N_NODES);
  k_scan2<<<1, 256, 0, stream>>>(bsum, NB);
  k_scan3<<<NB, 256, 0, stream>>>(scanned, bsum, counts, row_ptr, cursor, N_NODES);
  k_fill<<<(N_EDGES+255)/256, 256, 0, stream>>>(src, dst, cursor, esrc, N_EDGES);

  // ---- weight prep (+bias fold) + h->xcat ----
  k_wprep<<<dim3(16, 14), 256, 0, stream>>>(c0W1, cW1, cW2, p0W, pW, p0b, pb, wb, whead, ball);
  k_f2b<<<(N_NODES*16 + 255)/256, 256, 0, stream>>>(h, xcat, N_NODES*16);

  const float invM = 1.0f / (float)N_NODES;
  for (int i = 0; i < N_CONV; ++i){
    int K1 = (i == 0) ? IN_DIM : HID;
    const ushort_t* xin = (i == 0) ? xcat : (xcat + 128 + (size_t)(i-1)*HID);
    if (i == 0)
      k_agg<IN_DIM><<<(N_NODES*64+255)/256, 256, 0, stream>>>(xin, row_ptr, esrc, aggb, N_NODES);
    else
      k_agg<HID><<<(N_NODES*64+255)/256, 256, 0, stream>>>(xin, row_ptr, esrc, aggb, N_NODES);

    float* sums1 = sums8 + (size_t)(2*i)*512;
    float* sums2 = sums8 + (size_t)(2*i+1)*512;

    // GEMM1: tt = aggb @ W1  (+ fused stats of rounded output)
    const ushort_t* W1T = (i == 0) ? wb : (wb + 32768 + (size_t)(i-1)*65536);
    k_mgemm<128, 128, 0><<<dim3(2, MPAD/128), 256, 0, stream>>>(
        (const bf16*)aggb, (const bf16*)W1T, tt, nullptr, sums1,
        nullptr, nullptr, nullptr, N_NODES, HID, K1, invM);

    // GEMM2: aggb = relu(bn1(tt)) @ W2  (BN1+ReLU fused into A-staging; fused stats)
    const ushort_t* W2T = wb + 229376 + (size_t)i*65536;
    k_mgemm<128, 128, 2><<<dim3(2, MPAD/128), 256, 0, stream>>>(
        (const bf16*)tt, (const bf16*)W2T, aggb, nullptr, sums2,
        sums1, bn1g + i*HID, bn1b + i*HID, N_NODES, HID, HID, invM);

    // BN2+ReLU -> xcat slice
    k_bnrelu<<<(N_NODES*32 + 255)/256, 256, 0, stream>>>(
        aggb, sums2, bn2g + i*HID, bn2b + i*HID, xcat + 128 + (size_t)i*HID, KCAT, N_NODES, invM);
  }

  // ---- consolidated jumping-knowledge head GEMM: out = xcat @ whead^T + ball ----
  k_mgemm<128, 64, 1><<<dim3(1, MPAD/128), 128, 0, stream>>>(
      (const bf16*)xcat, (const bf16*)whead, out, ball, nullptr,
      nullptr, nullptr, nullptr, N_NODES, OUT_DIM, KCAT, invM);
}

// Round 6
// 675.487 us; speedup vs baseline: 3.2969x; 1.0055x over previous
//
#include <hip/hip_runtime.h>

#define N_NODES 50000
#define MPAD    50176
#define N_EDGES 800000
#define IN_DIM 128
#define HID 256
#define OUT_DIM 64
#define N_CONV 4
#define KCAT 1152   // 128 + 4*256

typedef __bf16 bf16;
typedef __attribute__((ext_vector_type(8))) __bf16 bf16x8;
typedef __attribute__((ext_vector_type(4))) float f32x4;
typedef unsigned short ushort_t;

__device__ __forceinline__ unsigned short f2b(float f){
  unsigned u = __float_as_uint(f);
  u += 0x7fffu + ((u >> 16) & 1u);
  return (unsigned short)(u >> 16);
}
__device__ __forceinline__ float b2f_lo(unsigned v){ return __uint_as_float(v << 16); }
__device__ __forceinline__ float b2f_hi(unsigned v){ return __uint_as_float(v & 0xffff0000u); }

__device__ __forceinline__ void stage16(const void* g, void* l){
  __builtin_amdgcn_global_load_lds((const __attribute__((address_space(1))) unsigned int*)g,
                                   (__attribute__((address_space(3))) unsigned int*)l, 16, 0, 0);
}

// ---------------- CSR build ----------------
__global__ void k_count(const int* __restrict__ dst, int* __restrict__ cnt, int ne){
  int e = blockIdx.x*blockDim.x + threadIdx.x;
  if (e < ne) atomicAdd(&cnt[dst[e]], 1);
}

__global__ void k_scan1(const int* __restrict__ cnt, int* __restrict__ scanned,
                        int* __restrict__ bsum, int n){
  int i = blockIdx.x*256 + threadIdx.x;
  int v = (i < n) ? cnt[i] : 0;
  int lane = threadIdx.x & 63;
  #pragma unroll
  for (int off = 1; off < 64; off <<= 1){
    int t = __shfl_up(v, off, 64);
    if (lane >= off) v += t;
  }
  __shared__ int wsum[4];
  int wv = threadIdx.x >> 6;
  if (lane == 63) wsum[wv] = v;
  __syncthreads();
  if (threadIdx.x == 0){
    int s = 0;
    #pragma unroll
    for (int k = 0; k < 4; ++k){ int t = wsum[k]; wsum[k] = s; s += t; }
    bsum[blockIdx.x] = s;
  }
  __syncthreads();
  v += wsum[wv];
  if (i < n) scanned[i] = v;
}

__global__ void k_scan2(int* __restrict__ bsum, int nb){
  __shared__ int sd[256];
  int i = threadIdx.x;
  sd[i] = (i < nb) ? bsum[i] : 0;
  __syncthreads();
  #pragma unroll
  for (int off = 1; off < 256; off <<= 1){
    int t = (i >= off) ? sd[i-off] : 0;
    __syncthreads();
    sd[i] += t;
    __syncthreads();
  }
  if (i < nb) bsum[i] = sd[i];
}

__global__ void k_scan3(const int* __restrict__ scanned, const int* __restrict__ bsum,
                        const int* __restrict__ cnt, int* __restrict__ row_ptr,
                        int* __restrict__ cursor, int n){
  int i = blockIdx.x*256 + threadIdx.x;
  if (i < n){
    int off = (blockIdx.x > 0) ? bsum[blockIdx.x-1] : 0;
    int inc = scanned[i] + off;
    row_ptr[i+1] = inc;
    cursor[i] = inc - cnt[i];
  }
  if (i == 0) row_ptr[0] = 0;
}

__global__ void k_fill(const int* __restrict__ src, const int* __restrict__ dst,
                       int* __restrict__ cursor, int* __restrict__ esrc, int ne){
  int e = blockIdx.x*blockDim.x + threadIdx.x;
  if (e < ne){
    int p = atomicAdd(&cursor[dst[e]], 1);
    esrc[p] = src[e];
  }
}

// ---------------- aggregation from xcat slice (bf16, fp32 accum, 8x MLP) ----------------
template<int D>
__global__ void k_agg(const ushort_t* __restrict__ x, const int* __restrict__ rp,
                      const int* __restrict__ es, ushort_t* __restrict__ agg, int n){
  int gw = (int)((blockIdx.x*(size_t)blockDim.x + threadIdx.x) >> 6);
  int lane = threadIdx.x & 63;
  if (gw >= n) return;
  if (D == 256){
    const uint2* xp = (const uint2*)x; const int S = KCAT/4;
    uint2 v = xp[(size_t)gw*S + lane];
    float a0=b2f_lo(v.x), a1=b2f_hi(v.x), a2=b2f_lo(v.y), a3=b2f_hi(v.y);
    float c0=0.f, c1=0.f, c2=0.f, c3=0.f;
    int e = rp[gw], e1 = rp[gw+1];
    for (; e + 8 <= e1; e += 8){
      uint2 w[8];
      #pragma unroll
      for (int u = 0; u < 8; ++u) w[u] = xp[(size_t)es[e+u]*S + lane];
      #pragma unroll
      for (int u = 0; u < 8; u += 2){
        a0 += b2f_lo(w[u].x);   a1 += b2f_hi(w[u].x);   a2 += b2f_lo(w[u].y);   a3 += b2f_hi(w[u].y);
        c0 += b2f_lo(w[u+1].x); c1 += b2f_hi(w[u+1].x); c2 += b2f_lo(w[u+1].y); c3 += b2f_hi(w[u+1].y);
      }
    }
    for (; e + 2 <= e1; e += 2){
      uint2 w0 = xp[(size_t)es[e]*S + lane];
      uint2 w1 = xp[(size_t)es[e+1]*S + lane];
      a0 += b2f_lo(w0.x); a1 += b2f_hi(w0.x); a2 += b2f_lo(w0.y); a3 += b2f_hi(w0.y);
      c0 += b2f_lo(w1.x); c1 += b2f_hi(w1.x); c2 += b2f_lo(w1.y); c3 += b2f_hi(w1.y);
    }
    if (e < e1){
      uint2 w0 = xp[(size_t)es[e]*S + lane];
      a0 += b2f_lo(w0.x); a1 += b2f_hi(w0.x); a2 += b2f_lo(w0.y); a3 += b2f_hi(w0.y);
    }
    a0 += c0; a1 += c1; a2 += c2; a3 += c3;
    unsigned o0 = (unsigned)f2b(a0) | ((unsigned)f2b(a1) << 16);
    unsigned o1 = (unsigned)f2b(a2) | ((unsigned)f2b(a3) << 16);
    *(uint2*)(agg + (size_t)gw*256 + lane*4) = make_uint2(o0, o1);
  } else {
    const unsigned* xp = (const unsigned*)x; const int S = KCAT/2;
    unsigned v = xp[(size_t)gw*S + lane];
    float a0 = b2f_lo(v), a1 = b2f_hi(v);
    float c0 = 0.f, c1 = 0.f;
    int e = rp[gw], e1 = rp[gw+1];
    for (; e + 8 <= e1; e += 8){
      unsigned w[8];
      #pragma unroll
      for (int u = 0; u < 8; ++u) w[u] = xp[(size_t)es[e+u]*S + lane];
      #pragma unroll
      for (int u = 0; u < 8; u += 2){
        a0 += b2f_lo(w[u]);   a1 += b2f_hi(w[u]);
        c0 += b2f_lo(w[u+1]); c1 += b2f_hi(w[u+1]);
      }
    }
    for (; e + 2 <= e1; e += 2){
      unsigned w0 = xp[(size_t)es[e]*S + lane];
      unsigned w1 = xp[(size_t)es[e+1]*S + lane];
      a0 += b2f_lo(w0); a1 += b2f_hi(w0);
      c0 += b2f_lo(w1); c1 += b2f_hi(w1);
    }
    if (e < e1){
      unsigned w0 = xp[(size_t)es[e]*S + lane];
      a0 += b2f_lo(w0); a1 += b2f_hi(w0);
    }
    a0 += c0; a1 += c1;
    unsigned o = (unsigned)f2b(a0) | ((unsigned)f2b(a1) << 16);
    *(unsigned*)(agg + (size_t)gw*128 + lane*2) = o;
  }
}

// ---------------- BN+ReLU (bf16 in, bf16 out, inline stats, strided output) ----------------
__global__ void k_bnrelu(const ushort_t* __restrict__ t, const float* __restrict__ sums,
                         const float* __restrict__ g, const float* __restrict__ b,
                         ushort_t* __restrict__ o, int ostride, int M, float invM){
  int idx = blockIdx.x*blockDim.x + threadIdx.x;
  if (idx >= M*(HID/8)) return;
  int row = idx >> 5, cg = (idx & 31) * 8;
  uint4 v = *(const uint4*)(t + (size_t)row*HID + cg);
  unsigned wv[4] = {v.x, v.y, v.z, v.w};
  unsigned ov[4];
  #pragma unroll
  for (int p = 0; p < 4; ++p){
    int c0 = cg + 2*p, c1 = c0 + 1;
    float m0 = sums[c0]*invM, m1 = sums[c1]*invM;
    float r0 = rsqrtf(sums[HID+c0]*invM - m0*m0 + 1e-5f);
    float r1 = rsqrtf(sums[HID+c1]*invM - m1*m1 + 1e-5f);
    float y0 = (b2f_lo(wv[p]) - m0)*r0*g[c0] + b[c0];
    float y1 = (b2f_hi(wv[p]) - m1)*r1*g[c1] + b[c1];
    y0 = y0 > 0.f ? y0 : 0.f; y1 = y1 > 0.f ? y1 : 0.f;
    ov[p] = (unsigned)f2b(y0) | ((unsigned)f2b(y1) << 16);
  }
  *(uint4*)(o + (size_t)row*ostride + cg) = make_uint4(ov[0], ov[1], ov[2], ov[3]);
}

// ---------------- h fp32 -> bf16 into xcat col 0..127 ----------------
__global__ void k_f2b(const float* __restrict__ in, ushort_t* __restrict__ xcat, int n8){
  int idx = blockIdx.x*blockDim.x + threadIdx.x;
  if (idx >= n8) return;
  int row = idx >> 4, cg = (idx & 15) * 8;
  float4 a = *(const float4*)(in + (size_t)row*IN_DIM + cg);
  float4 c = *(const float4*)(in + (size_t)row*IN_DIM + cg + 4);
  unsigned o0 = (unsigned)f2b(a.x) | ((unsigned)f2b(a.y) << 16);
  unsigned o1 = (unsigned)f2b(a.z) | ((unsigned)f2b(a.w) << 16);
  unsigned o2 = (unsigned)f2b(c.x) | ((unsigned)f2b(c.y) << 16);
  unsigned o3 = (unsigned)f2b(c.z) | ((unsigned)f2b(c.w) << 16);
  *(uint4*)(xcat + (size_t)row*KCAT + cg) = make_uint4(o0, o1, o2, o3);
}

// ---------------- weight transpose + convert (+ fused bias fold) ----------------
__global__ void k_wprep(const float* __restrict__ c0W1, const float* __restrict__ cW1,
                        const float* __restrict__ cW2, const float* __restrict__ p0W,
                        const float* __restrict__ pW,
                        const float* __restrict__ p0b, const float* __restrict__ pb,
                        ushort_t* __restrict__ wb, ushort_t* __restrict__ whead,
                        float* __restrict__ ball){
  int m = blockIdx.y;
  if (m == 13){
    if (blockIdx.x == 0 && threadIdx.x < OUT_DIM){
      int c = threadIdx.x;
      float v = p0b[c];
      #pragma unroll
      for (int i = 0; i < N_CONV; ++i) v += pb[i*OUT_DIM + c];
      ball[c] = v;
    }
    return;
  }
  const float* src; int R, C; ushort_t* dst; int dstride, dcol;
  if (m == 0){       src = c0W1;              R = 128; C = 256; dst = wb;                       dstride = 128;  dcol = 0; }
  else if (m <= 3){  src = cW1 + (m-1)*65536; R = 256; C = 256; dst = wb + 32768 + (m-1)*65536; dstride = 256;  dcol = 0; }
  else if (m <= 7){  src = cW2 + (m-4)*65536; R = 256; C = 256; dst = wb + 229376 + (m-4)*65536;dstride = 256;  dcol = 0; }
  else if (m == 8){  src = p0W;               R = 128; C = 64;  dst = whead;                    dstride = KCAT; dcol = 0; }
  else {             src = pW + (m-9)*16384;  R = 256; C = 64;  dst = whead;                    dstride = KCAT; dcol = 128 + (m-9)*256; }
  int tx = R/64, tiles = tx * (C/64);
  int t = blockIdx.x;
  if (t >= tiles) return;
  int sr0 = (t % tx)*64, sc0 = (t / tx)*64;
  __shared__ float ld[64][65];
  int c = threadIdx.x & 63, rq = threadIdx.x >> 6;
  #pragma unroll
  for (int i = 0; i < 16; ++i){
    int rr = i*4 + rq;
    ld[rr][c] = src[(size_t)(sr0+rr)*C + sc0 + c];
  }
  __syncthreads();
  #pragma unroll
  for (int i = 0; i < 16; ++i){
    int rr = i*4 + rq;
    dst[(size_t)(sc0+rr)*dstride + dcol + sr0 + c] = f2b(ld[c][rr]);
  }
}

// ---------------- MFMA GEMM: C[M,N] = A[M,K](bf16) @ BT[N,K](bf16)^T ----------------
// MODE 0: round acc->bf16, fused column stats from rounded values, bf16 C (all rows incl pad)
// MODE 1: fp32 C + bias[col], masked row<M
// MODE 2: like MODE 0, but A is reg-staged with fused BN(asums)+ReLU affine and pad-row zeroing
template<int BM, int BN, int MODE>
__global__ __launch_bounds__((BM/64)*(BN/64)*64)
void k_mgemm(const bf16* __restrict__ A, const bf16* __restrict__ BT,
             void* __restrict__ Cv, const float* __restrict__ bias,
             float* __restrict__ sums, const float* __restrict__ asums,
             const float* __restrict__ ag, const float* __restrict__ ab,
             int M, int N, int K, float invM)
{
  constexpr int NW  = (BM/64)*(BN/64);
  constexpr int WNT = BN/64;
  constexpr int ACH = BM/16, BCH = BN/16;
  __shared__ __align__(16) bf16 As[2*BM*32];
  __shared__ __align__(16) bf16 Bs[2*BN*32];
  __shared__ float sAf[MODE==2?256:1];
  __shared__ float tAf[MODE==2?256:1];
  const int tid = threadIdx.x;
  const int wid = tid >> 6, l = tid & 63;
  const int wm = wid / WNT, wn = wid % WNT;
  const int m0 = blockIdx.y * BM, n0 = blockIdx.x * BN;
  const int r = l & 15, q = l >> 4;
  const int fragByte = ((q ^ ((r >> 1) & 3)) << 4);
  const int wrow = l >> 2;
  const int wk = (((l & 3) ^ ((l >> 3) & 3)) << 3);

  if constexpr (MODE == 2){
    if (tid < 256){
      float m = asums[tid] * invM;
      float var = asums[256 + tid] * invM - m*m;
      float s = rsqrtf(var + 1e-5f) * ag[tid];
      sAf[tid] = s;
      tAf[tid] = ab[tid] - m*s;
    }
    __syncthreads();
  }

  auto STAGE = [&](int buf, int k0){
    #pragma unroll
    for (int c = 0; c < ACH/NW; ++c){
      int ch = wid + c*NW;
      if constexpr (MODE == 2){
        int grow = m0 + ch*16 + wrow;
        uint4 raw = *(const uint4*)(A + (size_t)grow*K + (k0 + wk));
        int kc = k0 + wk;
        unsigned rv[4] = {raw.x, raw.y, raw.z, raw.w};
        unsigned ov[4];
        #pragma unroll
        for (int p = 0; p < 4; ++p){
          int c0 = kc + 2*p, c1 = c0 + 1;
          float y0 = fmaf(b2f_lo(rv[p]), sAf[c0], tAf[c0]);
          float y1 = fmaf(b2f_hi(rv[p]), sAf[c1], tAf[c1]);
          y0 = y0 > 0.f ? y0 : 0.f; y1 = y1 > 0.f ? y1 : 0.f;
          ov[p] = (unsigned)f2b(y0) | ((unsigned)f2b(y1) << 16);
        }
        if (grow >= M){ ov[0]=0; ov[1]=0; ov[2]=0; ov[3]=0; }
        *(uint4*)((char*)As + buf*(BM*64) + ch*1024 + l*16) = make_uint4(ov[0],ov[1],ov[2],ov[3]);
      } else {
        const bf16* g = A + (size_t)(m0 + ch*16 + wrow)*K + (k0 + wk);
        stage16(g, (char*)As + buf*(BM*64) + ch*1024);
      }
    }
    #pragma unroll
    for (int c = 0; c < BCH/NW; ++c){
      int ch = wid + c*NW;
      const bf16* g = BT + (size_t)(n0 + ch*16 + wrow)*K + (k0 + wk);
      stage16(g, (char*)Bs + buf*(BN*64) + ch*1024);
    }
  };

  f32x4 acc[4][4] = {};
  const int nt = K >> 5;
  STAGE(0, 0);
  for (int t = 0; t < nt; ++t){
    int cur = t & 1;
    __syncthreads();
    if (t + 1 < nt) STAGE(cur ^ 1, (t + 1) << 5);
    bf16x8 af[4], bfr[4];
    #pragma unroll
    for (int mf = 0; mf < 4; ++mf)
      af[mf] = *(const bf16x8*)((const char*)As + cur*(BM*64) + (wm*64 + mf*16 + r)*64 + fragByte);
    #pragma unroll
    for (int nf = 0; nf < 4; ++nf)
      bfr[nf] = *(const bf16x8*)((const char*)Bs + cur*(BN*64) + (wn*64 + nf*16 + r)*64 + fragByte);
    #pragma unroll
    for (int mf = 0; mf < 4; ++mf)
      #pragma unroll
      for (int nf = 0; nf < 4; ++nf)
        acc[mf][nf] = __builtin_amdgcn_mfma_f32_16x16x32_bf16(af[mf], bfr[nf], acc[mf][nf], 0, 0, 0);
  }

  if (MODE == 0 || MODE == 2){
    ushort_t* Cb = (ushort_t*)Cv;
    float s1[4] = {0.f,0.f,0.f,0.f}, s2[4] = {0.f,0.f,0.f,0.f};
    #pragma unroll
    for (int mf = 0; mf < 4; ++mf){
      #pragma unroll
      for (int j = 0; j < 4; ++j){
        int row = m0 + wm*64 + mf*16 + q*4 + j;
        #pragma unroll
        for (int nf = 0; nf < 4; ++nf){
          unsigned short us = f2b(acc[mf][nf][j]);
          float vr = __uint_as_float((unsigned)us << 16);
          s1[nf] += vr; s2[nf] = fmaf(vr, vr, s2[nf]);
          Cb[(size_t)row*N + n0 + wn*64 + nf*16 + r] = us;
        }
      }
    }
    #pragma unroll
    for (int nf = 0; nf < 4; ++nf){
      float a = s1[nf], c = s2[nf];
      a += __shfl_xor(a, 16, 64); a += __shfl_xor(a, 32, 64);
      c += __shfl_xor(c, 16, 64); c += __shfl_xor(c, 32, 64);
      if (q == 0){
        int col = n0 + wn*64 + nf*16 + r;
        atomicAdd(&sums[col], a);
        atomicAdd(&sums[256 + col], c);
      }
    }
  } else {
    float* C = (float*)Cv;
    #pragma unroll
    for (int mf = 0; mf < 4; ++mf){
      #pragma unroll
      for (int j = 0; j < 4; ++j){
        int row = m0 + wm*64 + mf*16 + q*4 + j;
        if (row >= M) continue;
        #pragma unroll
        for (int nf = 0; nf < 4; ++nf){
          int col = n0 + wn*64 + nf*16 + r;
          C[(size_t)row*N + col] = acc[mf][nf][j] + bias[col];
        }
      }
    }
  }
}

extern "C" void kernel_launch(void* const* d_in, const int* in_sizes, int n_in,
                              void* d_out, int out_size, void* d_ws, size_t ws_size,
                              hipStream_t stream){
  const float* h    = (const float*)d_in[0];
  const float* c0W1 = (const float*)d_in[1];
  const float* cW1  = (const float*)d_in[2];
  const float* cW2  = (const float*)d_in[3];
  const float* bn1g = (const float*)d_in[4];
  const float* bn1b = (const float*)d_in[5];
  const float* bn2g = (const float*)d_in[6];
  const float* bn2b = (const float*)d_in[7];
  const float* p0W  = (const float*)d_in[8];
  const float* p0b  = (const float*)d_in[9];
  const float* pW   = (const float*)d_in[10];
  const float* pb   = (const float*)d_in[11];
  const int* src    = (const int*)d_in[12];
  const int* dst    = (const int*)d_in[13];
  float* out = (float*)d_out;

  char* w = (char*)d_ws;
  auto alloc = [&](size_t bytes)->char*{ char* p = w; w += (bytes + 255) & ~(size_t)255; return p; };
  ushort_t* xcat = (ushort_t*)alloc((size_t)MPAD*KCAT*2);
  ushort_t* aggb = (ushort_t*)alloc((size_t)MPAD*HID*2);
  ushort_t* tt   = (ushort_t*)alloc((size_t)MPAD*HID*2);
  ushort_t* wb   = (ushort_t*)alloc((size_t)491520*2);
  ushort_t* whead= (ushort_t*)alloc((size_t)OUT_DIM*KCAT*2);
  int* row_ptr   = (int*)alloc((N_NODES+1)*4);
  int* cursor    = (int*)alloc(N_NODES*4);
  int* counts    = (int*)alloc(N_NODES*4);
  int* esrc      = (int*)alloc(N_EDGES*4);
  int* scanned   = (int*)alloc(N_NODES*4);
  int* bsum      = (int*)alloc(256*4);
  float* sums8   = (float*)alloc(8*512*4);
  float* ball    = (float*)alloc(OUT_DIM*4);

  // pad-row zeroing (128-wide view for layer-0 GEMM1 + 256-wide view)
  hipMemsetAsync(aggb + (size_t)N_NODES*IN_DIM, 0, (size_t)(MPAD-N_NODES)*IN_DIM*2, stream);
  hipMemsetAsync(aggb + (size_t)N_NODES*HID,    0, (size_t)(MPAD-N_NODES)*HID*2,    stream);
  hipMemsetAsync(sums8, 0, 8*512*4, stream);

  // ---- CSR build (by dst) ----
  const int NB = (N_NODES + 255) / 256;
  hipMemsetAsync(counts, 0, N_NODES*4, stream);
  k_count<<<(N_EDGES+255)/256, 256, 0, stream>>>(dst, counts, N_EDGES);
  k_scan1<<<NB, 256, 0, stream>>>(counts, scanned, bsum, N_NODES);
  k_scan2<<<1, 256, 0, stream>>>(bsum, NB);
  k_scan3<<<NB, 256, 0, stream>>>(scanned, bsum, counts, row_ptr, cursor, N_NODES);
  k_fill<<<(N_EDGES+255)/256, 256, 0, stream>>>(src, dst, cursor, esrc, N_EDGES);

  // ---- weight prep (+bias fold) + h->xcat ----
  k_wprep<<<dim3(16, 14), 256, 0, stream>>>(c0W1, cW1, cW2, p0W, pW, p0b, pb, wb, whead, ball);
  k_f2b<<<(N_NODES*16 + 255)/256, 256, 0, stream>>>(h, xcat, N_NODES*16);

  const float invM = 1.0f / (float)N_NODES;
  for (int i = 0; i < N_CONV; ++i){
    int K1 = (i == 0) ? IN_DIM : HID;
    const ushort_t* xin = (i == 0) ? xcat : (xcat + 128 + (size_t)(i-1)*HID);
    if (i == 0)
      k_agg<IN_DIM><<<(N_NODES*64+255)/256, 256, 0, stream>>>(xin, row_ptr, esrc, aggb, N_NODES);
    else
      k_agg<HID><<<(N_NODES*64+255)/256, 256, 0, stream>>>(xin, row_ptr, esrc, aggb, N_NODES);

    float* sums1 = sums8 + (size_t)(2*i)*512;
    float* sums2 = sums8 + (size_t)(2*i+1)*512;

    // GEMM1: tt = aggb @ W1  (+ fused stats of rounded output) — single N-block, A read once
    const ushort_t* W1T = (i == 0) ? wb : (wb + 32768 + (size_t)(i-1)*65536);
    k_mgemm<64, 256, 0><<<dim3(1, MPAD/64), 256, 0, stream>>>(
        (const bf16*)aggb, (const bf16*)W1T, tt, nullptr, sums1,
        nullptr, nullptr, nullptr, N_NODES, HID, K1, invM);

    // GEMM2: aggb = relu(bn1(tt)) @ W2  (BN1+ReLU fused into A-staging, done once; fused stats)
    const ushort_t* W2T = wb + 229376 + (size_t)i*65536;
    k_mgemm<64, 256, 2><<<dim3(1, MPAD/64), 256, 0, stream>>>(
        (const bf16*)tt, (const bf16*)W2T, aggb, nullptr, sums2,
        sums1, bn1g + i*HID, bn1b + i*HID, N_NODES, HID, HID, invM);

    // BN2+ReLU -> xcat slice
    k_bnrelu<<<(N_NODES*32 + 255)/256, 256, 0, stream>>>(
        aggb, sums2, bn2g + i*HID, bn2b + i*HID, xcat + 128 + (size_t)i*HID, KCAT, N_NODES, invM);
  }

  // ---- consolidated jumping-knowledge head GEMM: out = xcat @ whead^T + ball ----
  k_mgemm<128, 64, 1><<<dim3(1, MPAD/128), 128, 0, stream>>>(
      (const bf16*)xcat, (const bf16*)whead, out, ball, nullptr,
      nullptr, nullptr, nullptr, N_NODES, OUT_DIM, KCAT, invM);
}